// Round 5
// baseline (12291.932 us; speedup 1.0000x reference)
//
#include <hip/hip_runtime.h>
#include <hip/hip_bf16.h>

// Problem dims: B=64, T=128, V=512, H=512, 4H=2048, 2H=1024, A=64, C+1=501
// ALL inputs fp32, output fp32.
// Precision design (R3 evidence: LN-LSTM chain amplifies per-step noise ~2400x;
// 2-way-split bf16 (~8e-6) -> absmax 1.9e-2 vs 1.02e-2 gate):
//   * 3-way bf16 split (hi/mid/lo, ~24 mantissa bits) + 6 MFMA products for
//     every GEMM in the amplified path  -> truncation ~2^-27
//   * xg (post-LN gate inputs) stored fp32 (never an MFMA operand)
//   * precise expf/tanhf in the recurrence
// Workspace (R4 evidence: ws_size = 256 MiB exactly; R4 overflowed at the
// 268,435,456-byte boundary -> abort): packed to 237.7 MiB via temporal
// aliasing of the hs1 region (xn / L0 weights / W_ih1 staged there; only
// W_hh1 needs a live region during scan L1).
#define LN_EPS 1e-5f

using bf16x8 = __attribute__((ext_vector_type(8))) short;
using f32x4  = __attribute__((ext_vector_type(4))) float;

__device__ __forceinline__ float bf2f(ushort u) {
    union { unsigned int i; float f; } v; v.i = ((unsigned int)u) << 16; return v.f;
}
__device__ __forceinline__ ushort f2bf(float f) {
    union { unsigned int i; float f; } v; v.f = f;
    unsigned int r = v.i + 0x7FFFu + ((v.i >> 16) & 1u);
    return (ushort)(r >> 16);
}
// 3-way split: x ~= a + b + c, residual ~2^-26|x|
__device__ __forceinline__ void split3(float x, ushort& a, ushort& b, ushort& c) {
    a = f2bf(x); float r = x - bf2f(a);
    b = f2bf(r); float r2 = r - bf2f(b);
    c = f2bf(r2);
}

__device__ __forceinline__ void blockReduceSum2(float& a, float& b, float* red) {
    #pragma unroll
    for (int off = 32; off > 0; off >>= 1) {
        a += __shfl_down(a, off, 64);
        b += __shfl_down(b, off, 64);
    }
    const int nw = blockDim.x >> 6;
    const int w = threadIdx.x >> 6;
    if ((threadIdx.x & 63) == 0) { red[2 * w] = a; red[2 * w + 1] = b; }
    __syncthreads();
    if (threadIdx.x == 0) {
        float sa = 0.f, sb = 0.f;
        for (int i = 0; i < nw; ++i) { sa += red[2 * i]; sb += red[2 * i + 1]; }
        red[10] = sa; red[11] = sb;
    }
    __syncthreads();
    a = red[10]; b = red[11];
    __syncthreads();
}

// ---------------- fp32 -> 3-way bf16 split staging ----------------
__global__ __launch_bounds__(256) void conv_split3_k(const float* __restrict__ src, ushort* __restrict__ d0,
                                                     ushort* __restrict__ d1, ushort* __restrict__ d2, int n4) {
    int i = blockIdx.x * 256 + threadIdx.x;
    if (i < n4) {
        float4 v = ((const float4*)src)[i];
        ushort4 a, b, c;
        split3(v.x, a.x, b.x, c.x); split3(v.y, a.y, b.y, c.y);
        split3(v.z, a.z, b.z, c.z); split3(v.w, a.w, b.w, c.w);
        ((ushort4*)d0)[i] = a; ((ushort4*)d1)[i] = b; ((ushort4*)d2)[i] = c;
    }
}

// ---------------- BatchNorm 1 ----------------
__global__ __launch_bounds__(256) void bn1_stats_k(const float* __restrict__ in, float* __restrict__ st) {
    int b = blockIdx.x, tid = threadIdx.x;
    float s10 = 0, s20 = 0, s11 = 0, s21 = 0;
    const float* p = in + (size_t)b * 128 * 512;
    for (int t = 0; t < 128; ++t) {
        float x0 = p[t * 512 + tid];
        float x1 = p[t * 512 + tid + 256];
        s10 += x0; s20 += x0 * x0; s11 += x1; s21 += x1 * x1;
    }
    atomicAdd(&st[tid], s10);       atomicAdd(&st[512 + tid], s20);
    atomicAdd(&st[tid + 256], s11); atomicAdd(&st[512 + tid + 256], s21);
}

__global__ void bn1_final_k(const float* __restrict__ st, const float* __restrict__ g,
                            const float* __restrict__ bb, float* __restrict__ ac) {
    int d = threadIdx.x + blockIdx.x * 256;
    if (d < 512) {
        float m = st[d] * (1.f / 8192.f);
        float v = st[512 + d] * (1.f / 8192.f) - m * m;
        float a = g[d] * rsqrtf(v + LN_EPS);
        ac[d] = a; ac[512 + d] = bb[d] - m * a;
    }
}

// xn[t*64+b][d] 3-split with (b,t)->(t,b) transpose
__global__ __launch_bounds__(128) void bn1_apply3_k(const float* __restrict__ in, const float* __restrict__ ac,
                                                    ushort* __restrict__ x0, ushort* __restrict__ x1,
                                                    ushort* __restrict__ x2) {
    int beta = blockIdx.x;           // t*64+b
    int t = beta >> 6, b = beta & 63;
    const float* src = in + ((size_t)b * 128 + t) * 512;
    #pragma unroll
    for (int k = 0; k < 4; ++k) {
        int d = threadIdx.x + 128 * k;
        ushort a, m, l;
        split3(ac[d] * src[d] + ac[512 + d], a, m, l);
        x0[(size_t)beta * 512 + d] = a;
        x1[(size_t)beta * 512 + d] = m;
        x2[(size_t)beta * 512 + d] = l;
    }
}

// ---------------- xg GEMM (3-split, 6 products): C[dir][m][n] fp32 ----------------
// grid (16, 64, 2), block 256 (2x2 waves, 64x64 per wave)
__global__ __launch_bounds__(256) void gemm6_k(const ushort* __restrict__ A0, const ushort* __restrict__ A1,
                                               const ushort* __restrict__ A2,
                                               const ushort* __restrict__ W0, const ushort* __restrict__ W1,
                                               const ushort* __restrict__ W2,
                                               float* __restrict__ C, int K) {
    const int dir = blockIdx.z;
    const ushort* Wp0 = W0 + (size_t)dir * 2048 * K;
    const ushort* Wp1 = W1 + (size_t)dir * 2048 * K;
    const ushort* Wp2 = W2 + (size_t)dir * 2048 * K;
    const int wave = threadIdx.x >> 6, lane = threadIdx.x & 63;
    const int l15 = lane & 15, kq = lane >> 4;
    const int m0 = blockIdx.y * 128 + (wave >> 1) * 64;
    const int n0 = blockIdx.x * 128 + (wave & 1) * 64;
    f32x4 acc[4][4];
    #pragma unroll
    for (int i = 0; i < 4; ++i)
        #pragma unroll
        for (int j = 0; j < 4; ++j) acc[i][j] = (f32x4){0.f, 0.f, 0.f, 0.f};
    for (int k0 = 0; k0 < K; k0 += 32) {
        bf16x8 a0[4], a1[4], a2[4], b0[4], b1[4], b2[4];
        #pragma unroll
        for (int i = 0; i < 4; ++i) {
            size_t o = (size_t)(m0 + i * 16 + l15) * K + k0 + kq * 8;
            a0[i] = *(const bf16x8*)(A0 + o);
            a1[i] = *(const bf16x8*)(A1 + o);
            a2[i] = *(const bf16x8*)(A2 + o);
        }
        #pragma unroll
        for (int j = 0; j < 4; ++j) {
            size_t o = (size_t)(n0 + j * 16 + l15) * K + k0 + kq * 8;
            b0[j] = *(const bf16x8*)(Wp0 + o);
            b1[j] = *(const bf16x8*)(Wp1 + o);
            b2[j] = *(const bf16x8*)(Wp2 + o);
        }
        #pragma unroll
        for (int i = 0; i < 4; ++i)
            #pragma unroll
            for (int j = 0; j < 4; ++j) {
                acc[i][j] = __builtin_amdgcn_mfma_f32_16x16x32_bf16(a2[i], b0[j], acc[i][j], 0, 0, 0);
                acc[i][j] = __builtin_amdgcn_mfma_f32_16x16x32_bf16(a1[i], b1[j], acc[i][j], 0, 0, 0);
                acc[i][j] = __builtin_amdgcn_mfma_f32_16x16x32_bf16(a0[i], b2[j], acc[i][j], 0, 0, 0);
                acc[i][j] = __builtin_amdgcn_mfma_f32_16x16x32_bf16(a1[i], b0[j], acc[i][j], 0, 0, 0);
                acc[i][j] = __builtin_amdgcn_mfma_f32_16x16x32_bf16(a0[i], b1[j], acc[i][j], 0, 0, 0);
                acc[i][j] = __builtin_amdgcn_mfma_f32_16x16x32_bf16(a0[i], b0[j], acc[i][j], 0, 0, 0);
            }
    }
    #pragma unroll
    for (int i = 0; i < 4; ++i)
        #pragma unroll
        for (int j = 0; j < 4; ++j)
            #pragma unroll
            for (int r = 0; r < 4; ++r)
                C[(size_t)dir * 8192 * 2048 + (size_t)(m0 + i * 16 + kq * 4 + r) * 2048 + n0 + j * 16 + l15]
                    = acc[i][j][r];
}

// ---------------- in-place row LayerNorm fp32, rows of 2048; grid (8192,2) ----------------
__global__ __launch_bounds__(256) void ln_rows32_k(float* __restrict__ X, const float* __restrict__ lng,
                                                   const float* __restrict__ lnb) {
    __shared__ float red[12];
    const int dir = blockIdx.y;
    float* row = X + ((size_t)dir * 8192 + blockIdx.x) * 2048;
    const float* g = lng + dir * 4608;
    const float* bb = lnb + dir * 4608;
    const int tid = threadIdx.x;
    float4 v0 = ((const float4*)row)[tid], v1 = ((const float4*)row)[tid + 256];
    float s1 = v0.x + v0.y + v0.z + v0.w + v1.x + v1.y + v1.z + v1.w;
    float s2 = v0.x * v0.x + v0.y * v0.y + v0.z * v0.z + v0.w * v0.w
             + v1.x * v1.x + v1.y * v1.y + v1.z * v1.z + v1.w * v1.w;
    blockReduceSum2(s1, s2, red);
    float m = s1 * (1.f / 2048.f);
    float rs = rsqrtf(s2 * (1.f / 2048.f) - m * m + LN_EPS);
    float4 g0 = ((const float4*)g)[tid],  g1 = ((const float4*)g)[tid + 256];
    float4 b0 = ((const float4*)bb)[tid], b1 = ((const float4*)bb)[tid + 256];
    float4 o0, o1;
    o0.x = (v0.x - m) * rs * g0.x + b0.x; o0.y = (v0.y - m) * rs * g0.y + b0.y;
    o0.z = (v0.z - m) * rs * g0.z + b0.z; o0.w = (v0.w - m) * rs * g0.w + b0.w;
    o1.x = (v1.x - m) * rs * g1.x + b1.x; o1.y = (v1.y - m) * rs * g1.y + b1.y;
    o1.z = (v1.z - m) * rs * g1.z + b1.z; o1.w = (v1.w - m) * rs * g1.w + b1.w;
    ((float4*)row)[tid] = o0;
    ((float4*)row)[tid + 256] = o1;
}

// ---------------- software grid barrier (128 blocks, co-resident) ----------------
__device__ __forceinline__ void gbar(unsigned int* flags, unsigned int* gen, unsigned int e) {
    __syncthreads();
    if (blockIdx.x == 0) {
        if (threadIdx.x < 127) {
            unsigned int idx = threadIdx.x + 1;
            while (__hip_atomic_load(&flags[idx], __ATOMIC_ACQUIRE, __HIP_MEMORY_SCOPE_AGENT) < e)
                __builtin_amdgcn_s_sleep(1);
        }
        __syncthreads();
        if (threadIdx.x == 0)
            __hip_atomic_store(gen, e, __ATOMIC_RELEASE, __HIP_MEMORY_SCOPE_AGENT);
    } else {
        if (threadIdx.x == 0) {
            __hip_atomic_store(&flags[blockIdx.x], e, __ATOMIC_RELEASE, __HIP_MEMORY_SCOPE_AGENT);
            while (__hip_atomic_load(gen, __ATOMIC_ACQUIRE, __HIP_MEMORY_SCOPE_AGENT) < e)
                __builtin_amdgcn_s_sleep(1);
        }
        __syncthreads();
    }
    __syncthreads();
}

// ---------------- LSTM scan, one layer, both dirs; 128x256, software barrier ----------------
// Phase A: gates_raw[dir][b][n] = h[dir][b] @ whh[dir][n]^T (3-split, 6 products).
//   block beta: dir = beta>>6, cols (beta&63)*32..+31, all 64 batch rows.
// Phase B: row (dir=beta>>6, b=beta&63): LN(2048) + pointwise + LN(512), fp32 state.
__global__ __launch_bounds__(256) void lstm_scan3_k(
    const float* __restrict__ xg,
    const ushort* __restrict__ w0, const ushort* __restrict__ w1, const ushort* __restrict__ w2,
    const float* __restrict__ lng, const float* __restrict__ lnb,
    ushort* __restrict__ hb0, ushort* __restrict__ hb1, ushort* __restrict__ hb2,
    float* __restrict__ graw,
    ushort* __restrict__ hs0, ushort* __restrict__ hs1, ushort* __restrict__ hs2,
    unsigned int* __restrict__ flags, unsigned int* __restrict__ gen) {
    __shared__ float ldsg[2048];
    __shared__ float red[12];
    const int beta = blockIdx.x, tid = threadIdx.x;
    const int dirB = beta >> 6, bB = beta & 63;
    const int wave = tid >> 6, lane = tid & 63, l15 = lane & 15, kq = lane >> 4;
    // zero h state (all 3 levels)
    ushort2 z2; z2.x = 0; z2.y = 0;
    ((ushort2*)hb0)[(dirB * 64 + bB) * 256 + tid] = z2;
    ((ushort2*)hb1)[(dirB * 64 + bB) * 256 + tid] = z2;
    ((ushort2*)hb2)[(dirB * 64 + bB) * 256 + tid] = z2;
    float c0 = 0.f, c1 = 0.f;
    const float* g_hh = lng + dirB * 4608 + 2048;
    const float* b_hh = lnb + dirB * 4608 + 2048;
    const float gc0 = lng[dirB * 4608 + 4096 + tid];
    const float gc1 = lng[dirB * 4608 + 4096 + tid + 256];
    const float bc0 = lnb[dirB * 4608 + 4096 + tid];
    const float bc1 = lnb[dirB * 4608 + 4096 + tid + 256];
    // phase-A tile assignment: 4 waves cover 64 rows x 32 cols
    const int jj = wave >> 1, ip = wave & 1;
    const int nn = bB * 32 + jj * 16;
    const ushort* h0d = hb0 + dirB * 64 * 512;
    const ushort* h1d = hb1 + dirB * 64 * 512;
    const ushort* h2d = hb2 + dirB * 64 * 512;
    const ushort* w0d = w0 + (size_t)dirB * 2048 * 512;
    const ushort* w1d = w1 + (size_t)dirB * 2048 * 512;
    const ushort* w2d = w2 + (size_t)dirB * 2048 * 512;
    float* gr = graw + dirB * 64 * 2048;
    unsigned int e = 0;
    gbar(flags, gen, ++e);
    for (int s = 0; s < 128; ++s) {
        // -------- phase A: 6-product MFMA --------
        {
            f32x4 acc[2];
            acc[0] = (f32x4){0.f, 0.f, 0.f, 0.f};
            acc[1] = (f32x4){0.f, 0.f, 0.f, 0.f};
            for (int k0 = 0; k0 < 512; k0 += 32) {
                bf16x8 a0[2], a1[2], a2[2], b0, b1, b2;
                #pragma unroll
                for (int ii = 0; ii < 2; ++ii) {
                    int row = ip * 32 + ii * 16 + l15;
                    a0[ii] = *(const bf16x8*)(h0d + row * 512 + k0 + kq * 8);
                    a1[ii] = *(const bf16x8*)(h1d + row * 512 + k0 + kq * 8);
                    a2[ii] = *(const bf16x8*)(h2d + row * 512 + k0 + kq * 8);
                }
                size_t wo = (size_t)(nn + l15) * 512 + k0 + kq * 8;
                b0 = *(const bf16x8*)(w0d + wo);
                b1 = *(const bf16x8*)(w1d + wo);
                b2 = *(const bf16x8*)(w2d + wo);
                #pragma unroll
                for (int ii = 0; ii < 2; ++ii) {
                    acc[ii] = __builtin_amdgcn_mfma_f32_16x16x32_bf16(a2[ii], b0, acc[ii], 0, 0, 0);
                    acc[ii] = __builtin_amdgcn_mfma_f32_16x16x32_bf16(a1[ii], b1, acc[ii], 0, 0, 0);
                    acc[ii] = __builtin_amdgcn_mfma_f32_16x16x32_bf16(a0[ii], b2, acc[ii], 0, 0, 0);
                    acc[ii] = __builtin_amdgcn_mfma_f32_16x16x32_bf16(a1[ii], b0, acc[ii], 0, 0, 0);
                    acc[ii] = __builtin_amdgcn_mfma_f32_16x16x32_bf16(a0[ii], b1, acc[ii], 0, 0, 0);
                    acc[ii] = __builtin_amdgcn_mfma_f32_16x16x32_bf16(a0[ii], b0, acc[ii], 0, 0, 0);
                }
            }
            #pragma unroll
            for (int ii = 0; ii < 2; ++ii)
                #pragma unroll
                for (int r = 0; r < 4; ++r)
                    gr[(ip * 32 + ii * 16 + kq * 4 + r) * 2048 + nn + l15] = acc[ii][r];
        }
        gbar(flags, gen, ++e);
        // -------- phase B --------
        {
            const int time = dirB ? (127 - s) : s;
            const float4* grp = (const float4*)(graw + (dirB * 64 + bB) * 2048);
            float4 v0 = grp[tid], v1 = grp[tid + 256];
            float s1 = v0.x + v0.y + v0.z + v0.w + v1.x + v1.y + v1.z + v1.w;
            float s2 = v0.x * v0.x + v0.y * v0.y + v0.z * v0.z + v0.w * v0.w
                     + v1.x * v1.x + v1.y * v1.y + v1.z * v1.z + v1.w * v1.w;
            blockReduceSum2(s1, s2, red);
            float mu = s1 * (1.f / 2048.f);
            float rs = rsqrtf(s2 * (1.f / 2048.f) - mu * mu + LN_EPS);
            const float4* xr = (const float4*)(xg + ((size_t)dirB * 8192 + (size_t)time * 64 + bB) * 2048);
            float4 x0 = xr[tid], x1 = xr[tid + 256];
            float4 gh0 = ((const float4*)g_hh)[tid], gh1 = ((const float4*)g_hh)[tid + 256];
            float4 bh0 = ((const float4*)b_hh)[tid], bh1 = ((const float4*)b_hh)[tid + 256];
            float4 o0, o1;
            o0.x = x0.x + (v0.x - mu) * rs * gh0.x + bh0.x;
            o0.y = x0.y + (v0.y - mu) * rs * gh0.y + bh0.y;
            o0.z = x0.z + (v0.z - mu) * rs * gh0.z + bh0.z;
            o0.w = x0.w + (v0.w - mu) * rs * gh0.w + bh0.w;
            o1.x = x1.x + (v1.x - mu) * rs * gh1.x + bh1.x;
            o1.y = x1.y + (v1.y - mu) * rs * gh1.y + bh1.y;
            o1.z = x1.z + (v1.z - mu) * rs * gh1.z + bh1.z;
            o1.w = x1.w + (v1.w - mu) * rs * gh1.w + bh1.w;
            ((float4*)ldsg)[tid] = o0;
            ((float4*)ldsg)[tid + 256] = o1;
            __syncthreads();
            float gi0 = ldsg[tid],       gf0 = ldsg[512 + tid], gg0 = ldsg[1024 + tid], go0 = ldsg[1536 + tid];
            float gi1 = ldsg[256 + tid], gf1 = ldsg[768 + tid], gg1 = ldsg[1280 + tid], go1 = ldsg[1792 + tid];
            // precise activations: gain ~2400x makes __expf's ~2e-7 visible
            float si0 = 1.f / (1.f + expf(-gi0)), sf0 = 1.f / (1.f + expf(-gf0));
            float si1 = 1.f / (1.f + expf(-gi1)), sf1 = 1.f / (1.f + expf(-gf1));
            c0 = sf0 * c0 + si0 * tanhf(gg0);
            c1 = sf1 * c1 + si1 * tanhf(gg1);
            float t1 = c0 + c1, t2 = c0 * c0 + c1 * c1;
            __syncthreads();
            blockReduceSum2(t1, t2, red);
            float mc = t1 * (1.f / 512.f);
            float rc = rsqrtf(t2 * (1.f / 512.f) - mc * mc + LN_EPS);
            float so0 = 1.f / (1.f + expf(-go0)), so1 = 1.f / (1.f + expf(-go1));
            float h0 = so0 * tanhf((c0 - mc) * rc * gc0 + bc0);
            float h1 = so1 * tanhf((c1 - mc) * rc * gc1 + bc1);
            ushort ha0, hm0, hl0, ha1, hm1, hl1;
            split3(h0, ha0, hm0, hl0);
            split3(h1, ha1, hm1, hl1);
            size_t hro = (size_t)(dirB * 64 + bB) * 512;
            hb0[hro + tid] = ha0; hb0[hro + tid + 256] = ha1;
            hb1[hro + tid] = hm0; hb1[hro + tid + 256] = hm1;
            hb2[hro + tid] = hl0; hb2[hro + tid + 256] = hl1;
            size_t oro = ((size_t)time * 64 + bB) * 1024 + dirB * 512;
            hs0[oro + tid] = ha0; hs0[oro + tid + 256] = ha1;
            hs1[oro + tid] = hm0; hs1[oro + tid + 256] = hm1;
            hs2[oro + tid] = hl0; hs2[oro + tid + 256] = hl1;
        }
        gbar(flags, gen, ++e);
    }
}

// ---------------- BatchNorm 2 (reads 3-split hs) ----------------
__global__ __launch_bounds__(256) void bn2_stats3_k(const ushort* __restrict__ h0, const ushort* __restrict__ h1,
                                                    const ushort* __restrict__ h2, float* __restrict__ st) {
    int t = blockIdx.x, tid = threadIdx.x;
    float s1[4] = {0, 0, 0, 0}, s2[4] = {0, 0, 0, 0};
    size_t base = (size_t)t * 64 * 1024;
    for (int b = 0; b < 64; ++b) {
        #pragma unroll
        for (int k = 0; k < 4; ++k) {
            size_t o = base + b * 1024 + tid + 256 * k;
            float x = bf2f(h0[o]) + bf2f(h1[o]) + bf2f(h2[o]);
            s1[k] += x; s2[k] += x * x;
        }
    }
    #pragma unroll
    for (int k = 0; k < 4; ++k) {
        atomicAdd(&st[tid + 256 * k], s1[k]);
        atomicAdd(&st[1024 + tid + 256 * k], s2[k]);
    }
}

__global__ void bn2_final_k(const float* __restrict__ st, const float* __restrict__ g,
                            const float* __restrict__ bb, float* __restrict__ ac) {
    #pragma unroll
    for (int k = 0; k < 4; ++k) {
        int h = threadIdx.x + 256 * k;
        float m = st[h] * (1.f / 8192.f);
        float v = st[1024 + h] * (1.f / 8192.f) - m * m;
        float a = g[h] * rsqrtf(v + LN_EPS);
        ac[h] = a; ac[1024 + h] = bb[h] - m * a;
    }
}

__global__ __launch_bounds__(256) void bn2_apply3_k(const ushort* __restrict__ h0, const ushort* __restrict__ h1,
                                                    const ushort* __restrict__ h2, const float* __restrict__ ac,
                                                    float* __restrict__ y) {
    int beta = blockIdx.x;        // b*128+t
    int b = beta >> 7, t = beta & 127;
    size_t so = ((size_t)t * 64 + b) * 1024;
    float* dst = y + (size_t)beta * 1024;
    #pragma unroll
    for (int k = 0; k < 4; ++k) {
        int h = threadIdx.x + 256 * k;
        float x = bf2f(h0[so + h]) + bf2f(h1[so + h]) + bf2f(h2[so + h]);
        dst[h] = ac[h] * x + ac[1024 + h];
    }
}

// ---------------- attention (fp32) ----------------
__global__ __launch_bounds__(64) void att_scores_k(const float* __restrict__ y, const float* __restrict__ wo,
                                                   const float* __restrict__ bo, const float* __restrict__ uo,
                                                   float* __restrict__ sc) {
    int row = blockIdx.x;     // b*128+t
    int a = threadIdx.x;
    const float* yr = y + (size_t)row * 1024;
    float acc = bo[a];
    for (int h = 0; h < 1024; h += 4) {
        float4 yv = *(const float4*)(yr + h);
        acc += yv.x * wo[(h + 0) * 64 + a];
        acc += yv.y * wo[(h + 1) * 64 + a];
        acc += yv.z * wo[(h + 2) * 64 + a];
        acc += yv.w * wo[(h + 3) * 64 + a];
    }
    float p = tanhf(acc) * uo[a];
    #pragma unroll
    for (int off = 32; off > 0; off >>= 1) p += __shfl_down(p, off, 64);
    if (a == 0) sc[row] = p;
}

__global__ __launch_bounds__(128) void att_softmax_k(const float* __restrict__ sc, float* __restrict__ al) {
    __shared__ float red[8];
    int b = blockIdx.x, t = threadIdx.x;
    int lane = t & 63, w = t >> 6;
    float v = sc[b * 128 + t];
    float m = v;
    #pragma unroll
    for (int off = 32; off > 0; off >>= 1) m = fmaxf(m, __shfl_down(m, off, 64));
    if (lane == 0) red[w] = m;
    __syncthreads();
    m = fmaxf(red[0], red[1]);
    float e = expf(v - m);
    float sum = e;
    #pragma unroll
    for (int off = 32; off > 0; off >>= 1) sum += __shfl_down(sum, off, 64);
    if (lane == 0) red[2 + w] = sum;
    __syncthreads();
    sum = red[2] + red[3];
    al[b * 128 + t] = e / sum;
}

__global__ __launch_bounds__(256) void att_pool_k(const float* __restrict__ y, const float* __restrict__ al,
                                                  float* __restrict__ pooled) {
    int b = blockIdx.x, tid = threadIdx.x;
    float acc[4] = {0, 0, 0, 0};
    const float* yb = y + (size_t)b * 128 * 1024;
    for (int t = 0; t < 128; ++t) {
        float a = al[b * 128 + t];
        #pragma unroll
        for (int k = 0; k < 4; ++k) acc[k] += a * yb[t * 1024 + tid + 256 * k];
    }
    #pragma unroll
    for (int k = 0; k < 4; ++k) pooled[b * 1024 + tid + 256 * k] = acc[k];
}

__global__ __launch_bounds__(256) void out_gemv_k(const float* __restrict__ pooled, const float* __restrict__ W,
                                                  float* __restrict__ out) {
    int b = blockIdx.x, tid = threadIdx.x;
    const float* pb = pooled + b * 1024;
    #pragma unroll
    for (int rep = 0; rep < 2; ++rep) {
        int c = tid + rep * 256;
        if (c < 501) {
            float acc = W[(size_t)1024 * 501 + c];   // bias row (emb padded with 1)
            for (int h = 0; h < 1024; ++h) acc += pb[h] * W[(size_t)h * 501 + c];
            out[b * 501 + c] = acc;
        }
    }
}

extern "C" void kernel_launch(void* const* d_in, const int* in_sizes, int n_in,
                              void* d_out, int out_size, void* d_ws, size_t ws_size,
                              hipStream_t stream) {
    (void)in_sizes; (void)n_in; (void)out_size; (void)ws_size;
    const float* in_x  = (const float*)d_in[0];
    const float* bn1g  = (const float*)d_in[1];
    const float* bn1b  = (const float*)d_in[2];
    const float* bn2g  = (const float*)d_in[3];
    const float* bn2b  = (const float*)d_in[4];
    const float* w_ih0 = (const float*)d_in[5];
    const float* w_hh0 = (const float*)d_in[6];
    const float* lng0  = (const float*)d_in[7];
    const float* lnb0  = (const float*)d_in[8];
    const float* w_ih1 = (const float*)d_in[9];
    const float* w_hh1 = (const float*)d_in[10];
    const float* lng1  = (const float*)d_in[11];
    const float* lnb1  = (const float*)d_in[12];
    const float* w_om  = (const float*)d_in[13];
    const float* b_om  = (const float*)d_in[14];
    const float* u_om  = (const float*)d_in[15];
    const float* Wf    = (const float*)d_in[16];
    float* out = (float*)d_out;

    // ---- workspace: 237.7 MiB total (ws_size = 256 MiB, R4 evidence) ----
    char* ws = (char*)d_ws;
    size_t off = 0;
    auto alloc = [&](size_t bytes) { size_t o = off; off += (bytes + 255) & ~(size_t)255; return o; };
    float*  xg     = (float*)(ws + alloc(2ull * 8192 * 2048 * 4));    // 134.2 MB; ybuf aliases later
    ushort* hs0_0  = (ushort*)(ws + alloc(8192ull * 1024 * 2));       // hs0 3-split, 50.3 MB
    ushort* hs0_1  = (ushort*)(ws + alloc(8192ull * 1024 * 2));
    ushort* hs0_2  = (ushort*)(ws + alloc(8192ull * 1024 * 2));
    char*   hs1reg = ws + alloc(3ull * 8192 * 1024 * 2);              // hs1 region, 50.3 MB (aliased below)
    ushort* WH1_0  = (ushort*)(ws + alloc(2ull * 2048 * 512 * 2));    // W_hh1 3-split (live during scan L1)
    ushort* WH1_1  = (ushort*)(ws + alloc(2ull * 2048 * 512 * 2));
    ushort* WH1_2  = (ushort*)(ws + alloc(2ull * 2048 * 512 * 2));
    float*  graw   = (float*)(ws + alloc(2ull * 64 * 2048 * 4));      // 1 MB
    ushort* hb0    = (ushort*)(ws + alloc(2ull * 64 * 512 * 2));
    ushort* hb1    = (ushort*)(ws + alloc(2ull * 64 * 512 * 2));
    ushort* hb2    = (ushort*)(ws + alloc(2ull * 64 * 512 * 2));
    float*  st1    = (float*)(ws + alloc(1024 * 4));
    float*  ac1    = (float*)(ws + alloc(1024 * 4));
    float*  st2    = (float*)(ws + alloc(2048 * 4));
    float*  ac2    = (float*)(ws + alloc(2048 * 4));
    float*  sc     = (float*)(ws + alloc(8192 * 4));
    float*  al     = (float*)(ws + alloc(8192 * 4));
    float*  pooled = (float*)(ws + alloc(64ull * 1024 * 4));
    unsigned int* bar0 = (unsigned int*)(ws + alloc(256 * 4));
    unsigned int* bar1 = (unsigned int*)(ws + alloc(256 * 4));
    // hs1 region sub-aliases (all dead before scan L1 writes hs1):
    //   [0, 25.2M):    xn 3-split (bn1 -> gemm L0), then W_ih1 3-split (conv -> gemm L1)
    //   [25.2M,37.7M): W_ih0 3-split (conv -> gemm L0)
    //   [37.7M,50.3M): W_hh0 3-split (conv -> scan L0)
    ushort* hs1_0 = (ushort*)hs1reg;
    ushort* hs1_1 = (ushort*)(hs1reg + 16777216);
    ushort* hs1_2 = (ushort*)(hs1reg + 33554432);
    ushort* xn0   = (ushort*)(hs1reg + 0);
    ushort* xn1   = (ushort*)(hs1reg + 8388608);
    ushort* xn2   = (ushort*)(hs1reg + 16777216);
    ushort* WI0_0 = (ushort*)(hs1reg + 25165824);
    ushort* WI0_1 = (ushort*)(hs1reg + 29360128);
    ushort* WI0_2 = (ushort*)(hs1reg + 33554432 + 4194304);   // 37748736... careful: see note
    ushort* WH0_0 = (ushort*)(hs1reg + 41943040);
    ushort* WH0_1 = (ushort*)(hs1reg + 46137344);
    // W_hh0 needs 3 x 4,194,304 = 12.6 MB but only 8.4 MB remains after the
    // above; fix: pack W_ih0 at 25165824..37748736 and W_hh0_0/1 at
    // 37748736..46137344, W_hh0_2 goes to the WH1 region (dead until L1 conv).
    // Recompute cleanly:
    WI0_0 = (ushort*)(hs1reg + 25165824);
    WI0_1 = (ushort*)(hs1reg + 29360128);
    WI0_2 = (ushort*)(hs1reg + 33554432);                      // overlaps xn2? xn2 at 16777216..25165824 -> no. OK
    WH0_0 = (ushort*)(hs1reg + 37748736);
    WH0_1 = (ushort*)(hs1reg + 41943040);
    ushort* WH0_2 = (ushort*)(hs1reg + 46137344);              // ends at 50331648 = region end. OK
    ushort* WI1_0 = (ushort*)(hs1reg + 0);                     // W_ih1 3-split, after xn dead
    ushort* WI1_1 = (ushort*)(hs1reg + 8388608);
    ushort* WI1_2 = (ushort*)(hs1reg + 16777216);
    float*  ybuf  = (float*)xg;                                // 33.6 MB fp32, xg dead after scan L1

    // NOTE: xn2 occupies [16777216, 25165824) and WI0_2 [33554432, 37748736):
    // disjoint. xn (alive bn1->gemmL0) and WI0/WH0 (alive conv->scanL0) never
    // overlap each other; WI1 overwrites dead xn after scan L0. hs1 written
    // only by scan L1, when all of the above are dead.

    hipMemsetAsync(st1, 0, 1024 * 4, stream);
    hipMemsetAsync(st2, 0, 2048 * 4, stream);
    hipMemsetAsync(bar0, 0, 256 * 4, stream);
    hipMemsetAsync(bar1, 0, 256 * 4, stream);

    // stage layer-0 weights (3-split)
    conv_split3_k<<<2048, 256, 0, stream>>>(w_ih0, WI0_0, WI0_1, WI0_2, 2097152 / 4);
    conv_split3_k<<<2048, 256, 0, stream>>>(w_hh0, WH0_0, WH0_1, WH0_2, 2097152 / 4);

    // BN1 + transpose to (T,B,V), 3-split
    bn1_stats_k<<<64, 256, 0, stream>>>(in_x, st1);
    bn1_final_k<<<2, 256, 0, stream>>>(st1, bn1g, bn1b, ac1);
    bn1_apply3_k<<<8192, 128, 0, stream>>>(in_x, ac1, xn0, xn1, xn2);

    // ---- layer 0 ----
    gemm6_k<<<dim3(16, 64, 2), 256, 0, stream>>>(xn0, xn1, xn2, WI0_0, WI0_1, WI0_2, xg, 512);
    ln_rows32_k<<<dim3(8192, 2), 256, 0, stream>>>(xg, lng0, lnb0);
    lstm_scan3_k<<<128, 256, 0, stream>>>(xg, WH0_0, WH0_1, WH0_2, lng0, lnb0,
                                          hb0, hb1, hb2, graw, hs0_0, hs0_1, hs0_2, bar0, bar0 + 128);

    // stage layer-1 weights (xn / WI0 regions now dead)
    conv_split3_k<<<4096, 256, 0, stream>>>(w_ih1, WI1_0, WI1_1, WI1_2, 4194304 / 4);
    conv_split3_k<<<2048, 256, 0, stream>>>(w_hh1, WH1_0, WH1_1, WH1_2, 2097152 / 4);

    // ---- layer 1 ----
    gemm6_k<<<dim3(16, 64, 2), 256, 0, stream>>>(hs0_0, hs0_1, hs0_2, WI1_0, WI1_1, WI1_2, xg, 1024);
    ln_rows32_k<<<dim3(8192, 2), 256, 0, stream>>>(xg, lng1, lnb1);
    lstm_scan3_k<<<128, 256, 0, stream>>>(xg, WH1_0, WH1_1, WH1_2, lng1, lnb1,
                                          hb0, hb1, hb2, graw, hs1_0, hs1_1, hs1_2, bar1, bar1 + 128);

    // BN2 -> y fp32 (B,T,2H); ybuf aliases dead xg
    bn2_stats3_k<<<128, 256, 0, stream>>>(hs1_0, hs1_1, hs1_2, st2);
    bn2_final_k<<<1, 256, 0, stream>>>(st2, bn2g, bn2b, ac2);
    bn2_apply3_k<<<8192, 256, 0, stream>>>(hs1_0, hs1_1, hs1_2, ac2, ybuf);

    // attention + output
    att_scores_k<<<8192, 64, 0, stream>>>(ybuf, w_om, b_om, u_om, sc);
    att_softmax_k<<<64, 128, 0, stream>>>(sc, al);
    att_pool_k<<<64, 256, 0, stream>>>(ybuf, al, pooled);
    out_gemv_k<<<64, 256, 0, stream>>>(pooled, Wf, out);
}

// Round 6
// 9881.699 us; speedup vs baseline: 1.2439x; 1.2439x over previous
//
#include <hip/hip_runtime.h>
#include <hip/hip_bf16.h>

// Problem dims: B=64, T=128, V=512, H=512, 4H=2048, 2H=1024, A=64, C+1=501
// ALL inputs fp32, output fp32.
// Precision (R3/R5 evidence: LN-LSTM chain amplifies per-step noise ~2400x;
// 3-way bf16 split + 6 MFMA products + fp32 xg/LN/pointwise -> absmax 2e-3,
// 5x under the 1.02e-2 gate): DO NOT reduce splits/products.
// Sync (R5 evidence: acquire/release agent atomics emit buffer_inv/buffer_wbl2
// per op -> ~20us/barrier, scans = 86% of 12.3ms): cross-block data + flags
// use RELAXED agent atomics (sc1, MALL-coherent, no L2 flush); all-to-all
// flag barrier; W_hh stays normally cached (L2-resident across steps).
// Workspace: ws_size = 256 MiB (R4); packed ~238 MiB via temporal aliasing.
#define LN_EPS 1e-5f

using bf16x8 = __attribute__((ext_vector_type(8))) short;
using f32x4  = __attribute__((ext_vector_type(4))) float;

__device__ __forceinline__ float bf2f(ushort u) {
    union { unsigned int i; float f; } v; v.i = ((unsigned int)u) << 16; return v.f;
}
__device__ __forceinline__ ushort f2bf(float f) {
    union { unsigned int i; float f; } v; v.f = f;
    unsigned int r = v.i + 0x7FFFu + ((v.i >> 16) & 1u);
    return (ushort)(r >> 16);
}
// 3-way split: x ~= a + b + c, residual ~2^-26|x|
__device__ __forceinline__ void split3(float x, ushort& a, ushort& b, ushort& c) {
    a = f2bf(x); float r = x - bf2f(a);
    b = f2bf(r); float r2 = r - bf2f(b);
    c = f2bf(r2);
}

// ---- coherent (MALL) access helpers: relaxed agent atomics -> sc1, no inv/wb ----
__device__ __forceinline__ unsigned long long ld_u64_c(const void* p) {
    return __hip_atomic_load((const unsigned long long*)p, __ATOMIC_RELAXED, __HIP_MEMORY_SCOPE_AGENT);
}
__device__ __forceinline__ unsigned ld_u32_c(const void* p) {
    return __hip_atomic_load((const unsigned*)p, __ATOMIC_RELAXED, __HIP_MEMORY_SCOPE_AGENT);
}
__device__ __forceinline__ void st_u32_c(void* p, unsigned v) {
    __hip_atomic_store((unsigned*)p, v, __ATOMIC_RELAXED, __HIP_MEMORY_SCOPE_AGENT);
}
__device__ __forceinline__ void st_f32_c(void* p, float v) {
    union { unsigned u; float f; } c; c.f = v; st_u32_c(p, c.u);
}
__device__ __forceinline__ bf16x8 ld_bf16x8_c(const ushort* p) {
    union { bf16x8 v; unsigned long long q[2]; } u;
    u.q[0] = ld_u64_c(p);
    u.q[1] = ld_u64_c(p + 4);
    return u.v;
}

__device__ __forceinline__ void blockReduceSum2(float& a, float& b, float* red) {
    #pragma unroll
    for (int off = 32; off > 0; off >>= 1) {
        a += __shfl_down(a, off, 64);
        b += __shfl_down(b, off, 64);
    }
    const int nw = blockDim.x >> 6;
    const int w = threadIdx.x >> 6;
    if ((threadIdx.x & 63) == 0) { red[2 * w] = a; red[2 * w + 1] = b; }
    __syncthreads();
    if (threadIdx.x == 0) {
        float sa = 0.f, sb = 0.f;
        for (int i = 0; i < nw; ++i) { sa += red[2 * i]; sb += red[2 * i + 1]; }
        red[10] = sa; red[11] = sb;
    }
    __syncthreads();
    a = red[10]; b = red[11];
    __syncthreads();
}

// ---------------- fp32 -> 3-way bf16 split staging ----------------
__global__ __launch_bounds__(256) void conv_split3_k(const float* __restrict__ src, ushort* __restrict__ d0,
                                                     ushort* __restrict__ d1, ushort* __restrict__ d2, int n4) {
    int i = blockIdx.x * 256 + threadIdx.x;
    if (i < n4) {
        float4 v = ((const float4*)src)[i];
        ushort4 a, b, c;
        split3(v.x, a.x, b.x, c.x); split3(v.y, a.y, b.y, c.y);
        split3(v.z, a.z, b.z, c.z); split3(v.w, a.w, b.w, c.w);
        ((ushort4*)d0)[i] = a; ((ushort4*)d1)[i] = b; ((ushort4*)d2)[i] = c;
    }
}

// ---------------- BatchNorm 1 ----------------
__global__ __launch_bounds__(256) void bn1_stats_k(const float* __restrict__ in, float* __restrict__ st) {
    int b = blockIdx.x, tid = threadIdx.x;
    float s10 = 0, s20 = 0, s11 = 0, s21 = 0;
    const float* p = in + (size_t)b * 128 * 512;
    for (int t = 0; t < 128; ++t) {
        float x0 = p[t * 512 + tid];
        float x1 = p[t * 512 + tid + 256];
        s10 += x0; s20 += x0 * x0; s11 += x1; s21 += x1 * x1;
    }
    atomicAdd(&st[tid], s10);       atomicAdd(&st[512 + tid], s20);
    atomicAdd(&st[tid + 256], s11); atomicAdd(&st[512 + tid + 256], s21);
}

__global__ void bn1_final_k(const float* __restrict__ st, const float* __restrict__ g,
                            const float* __restrict__ bb, float* __restrict__ ac) {
    int d = threadIdx.x + blockIdx.x * 256;
    if (d < 512) {
        float m = st[d] * (1.f / 8192.f);
        float v = st[512 + d] * (1.f / 8192.f) - m * m;
        float a = g[d] * rsqrtf(v + LN_EPS);
        ac[d] = a; ac[512 + d] = bb[d] - m * a;
    }
}

// xn[t*64+b][d] 3-split with (b,t)->(t,b) transpose
__global__ __launch_bounds__(128) void bn1_apply3_k(const float* __restrict__ in, const float* __restrict__ ac,
                                                    ushort* __restrict__ x0, ushort* __restrict__ x1,
                                                    ushort* __restrict__ x2) {
    int beta = blockIdx.x;           // t*64+b
    int t = beta >> 6, b = beta & 63;
    const float* src = in + ((size_t)b * 128 + t) * 512;
    #pragma unroll
    for (int k = 0; k < 4; ++k) {
        int d = threadIdx.x + 128 * k;
        ushort a, m, l;
        split3(ac[d] * src[d] + ac[512 + d], a, m, l);
        x0[(size_t)beta * 512 + d] = a;
        x1[(size_t)beta * 512 + d] = m;
        x2[(size_t)beta * 512 + d] = l;
    }
}

// ---------------- xg GEMM (3-split, 6 products): C[dir][m][n] fp32 ----------------
__global__ __launch_bounds__(256) void gemm6_k(const ushort* __restrict__ A0, const ushort* __restrict__ A1,
                                               const ushort* __restrict__ A2,
                                               const ushort* __restrict__ W0, const ushort* __restrict__ W1,
                                               const ushort* __restrict__ W2,
                                               float* __restrict__ C, int K) {
    const int dir = blockIdx.z;
    const ushort* Wp0 = W0 + (size_t)dir * 2048 * K;
    const ushort* Wp1 = W1 + (size_t)dir * 2048 * K;
    const ushort* Wp2 = W2 + (size_t)dir * 2048 * K;
    const int wave = threadIdx.x >> 6, lane = threadIdx.x & 63;
    const int l15 = lane & 15, kq = lane >> 4;
    const int m0 = blockIdx.y * 128 + (wave >> 1) * 64;
    const int n0 = blockIdx.x * 128 + (wave & 1) * 64;
    f32x4 acc[4][4];
    #pragma unroll
    for (int i = 0; i < 4; ++i)
        #pragma unroll
        for (int j = 0; j < 4; ++j) acc[i][j] = (f32x4){0.f, 0.f, 0.f, 0.f};
    for (int k0 = 0; k0 < K; k0 += 32) {
        bf16x8 a0[4], a1[4], a2[4], b0[4], b1[4], b2[4];
        #pragma unroll
        for (int i = 0; i < 4; ++i) {
            size_t o = (size_t)(m0 + i * 16 + l15) * K + k0 + kq * 8;
            a0[i] = *(const bf16x8*)(A0 + o);
            a1[i] = *(const bf16x8*)(A1 + o);
            a2[i] = *(const bf16x8*)(A2 + o);
        }
        #pragma unroll
        for (int j = 0; j < 4; ++j) {
            size_t o = (size_t)(n0 + j * 16 + l15) * K + k0 + kq * 8;
            b0[j] = *(const bf16x8*)(Wp0 + o);
            b1[j] = *(const bf16x8*)(Wp1 + o);
            b2[j] = *(const bf16x8*)(Wp2 + o);
        }
        #pragma unroll
        for (int i = 0; i < 4; ++i)
            #pragma unroll
            for (int j = 0; j < 4; ++j) {
                acc[i][j] = __builtin_amdgcn_mfma_f32_16x16x32_bf16(a2[i], b0[j], acc[i][j], 0, 0, 0);
                acc[i][j] = __builtin_amdgcn_mfma_f32_16x16x32_bf16(a1[i], b1[j], acc[i][j], 0, 0, 0);
                acc[i][j] = __builtin_amdgcn_mfma_f32_16x16x32_bf16(a0[i], b2[j], acc[i][j], 0, 0, 0);
                acc[i][j] = __builtin_amdgcn_mfma_f32_16x16x32_bf16(a1[i], b0[j], acc[i][j], 0, 0, 0);
                acc[i][j] = __builtin_amdgcn_mfma_f32_16x16x32_bf16(a0[i], b1[j], acc[i][j], 0, 0, 0);
                acc[i][j] = __builtin_amdgcn_mfma_f32_16x16x32_bf16(a0[i], b0[j], acc[i][j], 0, 0, 0);
            }
    }
    #pragma unroll
    for (int i = 0; i < 4; ++i)
        #pragma unroll
        for (int j = 0; j < 4; ++j)
            #pragma unroll
            for (int r = 0; r < 4; ++r)
                C[(size_t)dir * 8192 * 2048 + (size_t)(m0 + i * 16 + kq * 4 + r) * 2048 + n0 + j * 16 + l15]
                    = acc[i][j][r];
}

// ---------------- in-place row LayerNorm fp32, rows of 2048; grid (8192,2) ----------------
__global__ __launch_bounds__(256) void ln_rows32_k(float* __restrict__ X, const float* __restrict__ lng,
                                                   const float* __restrict__ lnb) {
    __shared__ float red[12];
    const int dir = blockIdx.y;
    float* row = X + ((size_t)dir * 8192 + blockIdx.x) * 2048;
    const float* g = lng + dir * 4608;
    const float* bb = lnb + dir * 4608;
    const int tid = threadIdx.x;
    float4 v0 = ((const float4*)row)[tid], v1 = ((const float4*)row)[tid + 256];
    float s1 = v0.x + v0.y + v0.z + v0.w + v1.x + v1.y + v1.z + v1.w;
    float s2 = v0.x * v0.x + v0.y * v0.y + v0.z * v0.z + v0.w * v0.w
             + v1.x * v1.x + v1.y * v1.y + v1.z * v1.z + v1.w * v1.w;
    blockReduceSum2(s1, s2, red);
    float m = s1 * (1.f / 2048.f);
    float rs = rsqrtf(s2 * (1.f / 2048.f) - m * m + LN_EPS);
    float4 g0 = ((const float4*)g)[tid],  g1 = ((const float4*)g)[tid + 256];
    float4 b0 = ((const float4*)bb)[tid], b1 = ((const float4*)bb)[tid + 256];
    float4 o0, o1;
    o0.x = (v0.x - m) * rs * g0.x + b0.x; o0.y = (v0.y - m) * rs * g0.y + b0.y;
    o0.z = (v0.z - m) * rs * g0.z + b0.z; o0.w = (v0.w - m) * rs * g0.w + b0.w;
    o1.x = (v1.x - m) * rs * g1.x + b1.x; o1.y = (v1.y - m) * rs * g1.y + b1.y;
    o1.z = (v1.z - m) * rs * g1.z + b1.z; o1.w = (v1.w - m) * rs * g1.w + b1.w;
    ((float4*)row)[tid] = o0;
    ((float4*)row)[tid + 256] = o1;
}

// ---------------- all-to-all grid barrier (128 blocks), relaxed sc1 flags ----------------
// __syncthreads() drains each wave's vmcnt (compiler emits full waitcnt before
// s_barrier), so prior sc1 data stores are globally visible before the flag store.
__device__ __forceinline__ void gbar2(unsigned int* flags, unsigned int e) {
    __builtin_amdgcn_s_waitcnt(0);
    __syncthreads();
    if (threadIdx.x == 0)
        st_u32_c(&flags[blockIdx.x * 16], e);
    if (threadIdx.x < 128) {
        while (ld_u32_c(&flags[threadIdx.x * 16]) < e)
            __builtin_amdgcn_s_sleep(2);
    }
    __syncthreads();
}

// ---------------- LSTM scan, one layer, both dirs; 128x256 ----------------
// Phase A: block beta -> (dir=beta>>6) gate cols (beta&63)*32..+31, all 64 rows,
//   3-split 6-product MFMA; h read via sc1 u64, gates written via sc1 u32.
// Phase B: block beta -> row (dir, b=beta&63); thread owns gate cols 2t,2t+1.
//   No LDS transpose. fp32 state; h written as packed-u32 sc1 (3 planes).
__global__ __launch_bounds__(256) void lstm_scan4_k(
    const float* __restrict__ xg,
    const ushort* __restrict__ w0, const ushort* __restrict__ w1, const ushort* __restrict__ w2,
    const float* __restrict__ lng, const float* __restrict__ lnb,
    ushort* __restrict__ hb0, ushort* __restrict__ hb1, ushort* __restrict__ hb2,
    float* __restrict__ graw,
    ushort* __restrict__ hs0, ushort* __restrict__ hs1, ushort* __restrict__ hs2,
    unsigned int* __restrict__ flags) {
    __shared__ float red[12];
    const int beta = blockIdx.x, tid = threadIdx.x;
    const int dirB = beta >> 6, bB = beta & 63;
    const int wave = tid >> 6, lane = tid & 63, l15 = lane & 15, kq = lane >> 4;
    const size_t hro = (size_t)(dirB * 64 + bB) * 512;
    // zero own h row (sc1: cross-XCD phase-A readers go through MALL)
    st_u32_c((unsigned*)(hb0 + hro) + tid, 0u);
    st_u32_c((unsigned*)(hb1 + hro) + tid, 0u);
    st_u32_c((unsigned*)(hb2 + hro) + tid, 0u);
    float c0 = 0.f, c1 = 0.f;
    const float* g_hh = lng + dirB * 4608 + 2048;
    const float* b_hh = lnb + dirB * 4608 + 2048;
    const float2 gcv = ((const float2*)(lng + dirB * 4608 + 4096))[tid];
    const float2 bcv = ((const float2*)(lnb + dirB * 4608 + 4096))[tid];
    // phase-A tile assignment: 4 waves cover 64 rows x 32 cols
    const int jj = wave >> 1, ip = wave & 1;
    const int nn = bB * 32 + jj * 16;
    const ushort* h0d = hb0 + (size_t)dirB * 64 * 512;
    const ushort* h1d = hb1 + (size_t)dirB * 64 * 512;
    const ushort* h2d = hb2 + (size_t)dirB * 64 * 512;
    const ushort* w0d = w0 + (size_t)dirB * 2048 * 512;
    const ushort* w1d = w1 + (size_t)dirB * 2048 * 512;
    const ushort* w2d = w2 + (size_t)dirB * 2048 * 512;
    float* gr = graw + dirB * 64 * 2048;
    unsigned int e = 0;
    gbar2(flags, ++e);
    for (int s = 0; s < 128; ++s) {
        // -------- phase A: 6-product MFMA; W normal-cached, h via sc1 --------
        {
            f32x4 acc[2];
            acc[0] = (f32x4){0.f, 0.f, 0.f, 0.f};
            acc[1] = (f32x4){0.f, 0.f, 0.f, 0.f};
            for (int k0 = 0; k0 < 512; k0 += 32) {
                size_t wo = (size_t)(nn + l15) * 512 + k0 + kq * 8;
                bf16x8 b0 = *(const bf16x8*)(w0d + wo);
                bf16x8 b1 = *(const bf16x8*)(w1d + wo);
                bf16x8 b2 = *(const bf16x8*)(w2d + wo);
                #pragma unroll
                for (int ii = 0; ii < 2; ++ii) {
                    size_t ho = (size_t)(ip * 32 + ii * 16 + l15) * 512 + k0 + kq * 8;
                    bf16x8 a0 = ld_bf16x8_c(h0d + ho);
                    bf16x8 a1 = ld_bf16x8_c(h1d + ho);
                    bf16x8 a2 = ld_bf16x8_c(h2d + ho);
                    acc[ii] = __builtin_amdgcn_mfma_f32_16x16x32_bf16(a2, b0, acc[ii], 0, 0, 0);
                    acc[ii] = __builtin_amdgcn_mfma_f32_16x16x32_bf16(a1, b1, acc[ii], 0, 0, 0);
                    acc[ii] = __builtin_amdgcn_mfma_f32_16x16x32_bf16(a0, b2, acc[ii], 0, 0, 0);
                    acc[ii] = __builtin_amdgcn_mfma_f32_16x16x32_bf16(a1, b0, acc[ii], 0, 0, 0);
                    acc[ii] = __builtin_amdgcn_mfma_f32_16x16x32_bf16(a0, b1, acc[ii], 0, 0, 0);
                    acc[ii] = __builtin_amdgcn_mfma_f32_16x16x32_bf16(a0, b0, acc[ii], 0, 0, 0);
                }
            }
            #pragma unroll
            for (int ii = 0; ii < 2; ++ii)
                #pragma unroll
                for (int r = 0; r < 4; ++r)
                    st_f32_c(&gr[(ip * 32 + ii * 16 + kq * 4 + r) * 2048 + nn + l15], acc[ii][r]);
        }
        gbar2(flags, ++e);
        // -------- phase B: own row; thread owns gate cols 2t, 2t+1 --------
        {
            const int time = dirB ? (127 - s) : s;
            const float* grow = gr + bB * 2048;
            const int base = 2 * tid;
            float v[8];
            #pragma unroll
            for (int j = 0; j < 4; ++j) {
                union { unsigned long long q; float f[2]; } c;
                c.q = ld_u64_c(&grow[j * 512 + base]);
                v[2 * j] = c.f[0]; v[2 * j + 1] = c.f[1];
            }
            float s1 = 0.f, s2 = 0.f;
            #pragma unroll
            for (int k = 0; k < 8; ++k) { s1 += v[k]; s2 += v[k] * v[k]; }
            blockReduceSum2(s1, s2, red);
            float mu = s1 * (1.f / 2048.f);
            float rs = rsqrtf(s2 * (1.f / 2048.f) - mu * mu + LN_EPS);
            const float2* xr = (const float2*)(xg + ((size_t)dirB * 8192 + (size_t)time * 64 + bB) * 2048);
            float nv[8];
            #pragma unroll
            for (int j = 0; j < 4; ++j) {
                float2 xv = xr[tid + 256 * j];
                float2 gh = ((const float2*)g_hh)[tid + 256 * j];
                float2 bh = ((const float2*)b_hh)[tid + 256 * j];
                nv[2 * j]     = xv.x + (v[2 * j]     - mu) * rs * gh.x + bh.x;
                nv[2 * j + 1] = xv.y + (v[2 * j + 1] - mu) * rs * gh.y + bh.y;
            }
            float si0 = 1.f / (1.f + expf(-nv[0])), si1 = 1.f / (1.f + expf(-nv[1]));
            float sf0 = 1.f / (1.f + expf(-nv[2])), sf1 = 1.f / (1.f + expf(-nv[3]));
            c0 = sf0 * c0 + si0 * tanhf(nv[4]);
            c1 = sf1 * c1 + si1 * tanhf(nv[5]);
            float t1 = c0 + c1, t2 = c0 * c0 + c1 * c1;
            blockReduceSum2(t1, t2, red);
            float mc = t1 * (1.f / 512.f);
            float rc = rsqrtf(t2 * (1.f / 512.f) - mc * mc + LN_EPS);
            float so0 = 1.f / (1.f + expf(-nv[6])), so1 = 1.f / (1.f + expf(-nv[7]));
            float h0v = so0 * tanhf((c0 - mc) * rc * gcv.x + bcv.x);
            float h1v = so1 * tanhf((c1 - mc) * rc * gcv.y + bcv.y);
            ushort a0, m0, l0, a1, m1, l1;
            split3(h0v, a0, m0, l0);
            split3(h1v, a1, m1, l1);
            unsigned p0 = (unsigned)a0 | ((unsigned)a1 << 16);
            unsigned p1 = (unsigned)m0 | ((unsigned)m1 << 16);
            unsigned p2 = (unsigned)l0 | ((unsigned)l1 << 16);
            st_u32_c((unsigned*)(hb0 + hro) + tid, p0);
            st_u32_c((unsigned*)(hb1 + hro) + tid, p1);
            st_u32_c((unsigned*)(hb2 + hro) + tid, p2);
            size_t oro = ((size_t)time * 64 + bB) * 1024 + dirB * 512;
            ((unsigned*)(hs0 + oro))[tid] = p0;    // hs read only after kernel end:
            ((unsigned*)(hs1 + oro))[tid] = p1;    // normal stores are fine
            ((unsigned*)(hs2 + oro))[tid] = p2;
        }
        gbar2(flags, ++e);
    }
}

// ---------------- BatchNorm 2 (reads 3-split hs) ----------------
__global__ __launch_bounds__(256) void bn2_stats3_k(const ushort* __restrict__ h0, const ushort* __restrict__ h1,
                                                    const ushort* __restrict__ h2, float* __restrict__ st) {
    int t = blockIdx.x, tid = threadIdx.x;
    float s1[4] = {0, 0, 0, 0}, s2[4] = {0, 0, 0, 0};
    size_t base = (size_t)t * 64 * 1024;
    for (int b = 0; b < 64; ++b) {
        #pragma unroll
        for (int k = 0; k < 4; ++k) {
            size_t o = base + b * 1024 + tid + 256 * k;
            float x = bf2f(h0[o]) + bf2f(h1[o]) + bf2f(h2[o]);
            s1[k] += x; s2[k] += x * x;
        }
    }
    #pragma unroll
    for (int k = 0; k < 4; ++k) {
        atomicAdd(&st[tid + 256 * k], s1[k]);
        atomicAdd(&st[1024 + tid + 256 * k], s2[k]);
    }
}

__global__ void bn2_final_k(const float* __restrict__ st, const float* __restrict__ g,
                            const float* __restrict__ bb, float* __restrict__ ac) {
    #pragma unroll
    for (int k = 0; k < 4; ++k) {
        int h = threadIdx.x + 256 * k;
        float m = st[h] * (1.f / 8192.f);
        float v = st[1024 + h] * (1.f / 8192.f) - m * m;
        float a = g[h] * rsqrtf(v + LN_EPS);
        ac[h] = a; ac[1024 + h] = bb[h] - m * a;
    }
}

__global__ __launch_bounds__(256) void bn2_apply3_k(const ushort* __restrict__ h0, const ushort* __restrict__ h1,
                                                    const ushort* __restrict__ h2, const float* __restrict__ ac,
                                                    float* __restrict__ y) {
    int beta = blockIdx.x;        // b*128+t
    int b = beta >> 7, t = beta & 127;
    size_t so = ((size_t)t * 64 + b) * 1024;
    float* dst = y + (size_t)beta * 1024;
    #pragma unroll
    for (int k = 0; k < 4; ++k) {
        int h = threadIdx.x + 256 * k;
        float x = bf2f(h0[so + h]) + bf2f(h1[so + h]) + bf2f(h2[so + h]);
        dst[h] = ac[h] * x + ac[1024 + h];
    }
}

// ---------------- attention (fp32) ----------------
__global__ __launch_bounds__(64) void att_scores_k(const float* __restrict__ y, const float* __restrict__ wo,
                                                   const float* __restrict__ bo, const float* __restrict__ uo,
                                                   float* __restrict__ sc) {
    int row = blockIdx.x;     // b*128+t
    int a = threadIdx.x;
    const float* yr = y + (size_t)row * 1024;
    float acc = bo[a];
    for (int h = 0; h < 1024; h += 4) {
        float4 yv = *(const float4*)(yr + h);
        acc += yv.x * wo[(h + 0) * 64 + a];
        acc += yv.y * wo[(h + 1) * 64 + a];
        acc += yv.z * wo[(h + 2) * 64 + a];
        acc += yv.w * wo[(h + 3) * 64 + a];
    }
    float p = tanhf(acc) * uo[a];
    #pragma unroll
    for (int off = 32; off > 0; off >>= 1) p += __shfl_down(p, off, 64);
    if (a == 0) sc[row] = p;
}

__global__ __launch_bounds__(128) void att_softmax_k(const float* __restrict__ sc, float* __restrict__ al) {
    __shared__ float red[8];
    int b = blockIdx.x, t = threadIdx.x;
    int lane = t & 63, w = t >> 6;
    float v = sc[b * 128 + t];
    float m = v;
    #pragma unroll
    for (int off = 32; off > 0; off >>= 1) m = fmaxf(m, __shfl_down(m, off, 64));
    if (lane == 0) red[w] = m;
    __syncthreads();
    m = fmaxf(red[0], red[1]);
    float e = expf(v - m);
    float sum = e;
    #pragma unroll
    for (int off = 32; off > 0; off >>= 1) sum += __shfl_down(sum, off, 64);
    if (lane == 0) red[2 + w] = sum;
    __syncthreads();
    sum = red[2] + red[3];
    al[b * 128 + t] = e / sum;
}

__global__ __launch_bounds__(256) void att_pool_k(const float* __restrict__ y, const float* __restrict__ al,
                                                  float* __restrict__ pooled) {
    int b = blockIdx.x, tid = threadIdx.x;
    float acc[4] = {0, 0, 0, 0};
    const float* yb = y + (size_t)b * 128 * 1024;
    for (int t = 0; t < 128; ++t) {
        float a = al[b * 128 + t];
        #pragma unroll
        for (int k = 0; k < 4; ++k) acc[k] += a * yb[t * 1024 + tid + 256 * k];
    }
    #pragma unroll
    for (int k = 0; k < 4; ++k) pooled[b * 1024 + tid + 256 * k] = acc[k];
}

__global__ __launch_bounds__(256) void out_gemv_k(const float* __restrict__ pooled, const float* __restrict__ W,
                                                  float* __restrict__ out) {
    int b = blockIdx.x, tid = threadIdx.x;
    const float* pb = pooled + b * 1024;
    #pragma unroll
    for (int rep = 0; rep < 2; ++rep) {
        int c = tid + rep * 256;
        if (c < 501) {
            float acc = W[(size_t)1024 * 501 + c];   // bias row (emb padded with 1)
            for (int h = 0; h < 1024; ++h) acc += pb[h] * W[(size_t)h * 501 + c];
            out[b * 501 + c] = acc;
        }
    }
}

extern "C" void kernel_launch(void* const* d_in, const int* in_sizes, int n_in,
                              void* d_out, int out_size, void* d_ws, size_t ws_size,
                              hipStream_t stream) {
    (void)in_sizes; (void)n_in; (void)out_size; (void)ws_size;
    const float* in_x  = (const float*)d_in[0];
    const float* bn1g  = (const float*)d_in[1];
    const float* bn1b  = (const float*)d_in[2];
    const float* bn2g  = (const float*)d_in[3];
    const float* bn2b  = (const float*)d_in[4];
    const float* w_ih0 = (const float*)d_in[5];
    const float* w_hh0 = (const float*)d_in[6];
    const float* lng0  = (const float*)d_in[7];
    const float* lnb0  = (const float*)d_in[8];
    const float* w_ih1 = (const float*)d_in[9];
    const float* w_hh1 = (const float*)d_in[10];
    const float* lng1  = (const float*)d_in[11];
    const float* lnb1  = (const float*)d_in[12];
    const float* w_om  = (const float*)d_in[13];
    const float* b_om  = (const float*)d_in[14];
    const float* u_om  = (const float*)d_in[15];
    const float* Wf    = (const float*)d_in[16];
    float* out = (float*)d_out;

    // ---- workspace: ~238 MiB of the 256 MiB budget ----
    char* ws = (char*)d_ws;
    size_t off = 0;
    auto alloc = [&](size_t bytes) { size_t o = off; off += (bytes + 255) & ~(size_t)255; return o; };
    float*  xg     = (float*)(ws + alloc(2ull * 8192 * 2048 * 4));    // 134.2 MB; ybuf aliases later
    ushort* hs0_0  = (ushort*)(ws + alloc(8192ull * 1024 * 2));       // hs0 3-split, 50.3 MB
    ushort* hs0_1  = (ushort*)(ws + alloc(8192ull * 1024 * 2));
    ushort* hs0_2  = (ushort*)(ws + alloc(8192ull * 1024 * 2));
    char*   hs1reg = ws + alloc(3ull * 8192 * 1024 * 2);              // hs1 region, 50.3 MB (aliased below)
    ushort* WH1_0  = (ushort*)(ws + alloc(2ull * 2048 * 512 * 2));    // W_hh1 3-split (live during scan L1)
    ushort* WH1_1  = (ushort*)(ws + alloc(2ull * 2048 * 512 * 2));
    ushort* WH1_2  = (ushort*)(ws + alloc(2ull * 2048 * 512 * 2));
    float*  graw   = (float*)(ws + alloc(2ull * 64 * 2048 * 4));      // 1 MB
    ushort* hb0    = (ushort*)(ws + alloc(2ull * 64 * 512 * 2));
    ushort* hb1    = (ushort*)(ws + alloc(2ull * 64 * 512 * 2));
    ushort* hb2    = (ushort*)(ws + alloc(2ull * 64 * 512 * 2));
    float*  st1    = (float*)(ws + alloc(1024 * 4));
    float*  ac1    = (float*)(ws + alloc(1024 * 4));
    float*  st2    = (float*)(ws + alloc(2048 * 4));
    float*  ac2    = (float*)(ws + alloc(2048 * 4));
    float*  sc     = (float*)(ws + alloc(8192 * 4));
    float*  al     = (float*)(ws + alloc(8192 * 4));
    float*  pooled = (float*)(ws + alloc(64ull * 1024 * 4));
    unsigned int* bar0 = (unsigned int*)(ws + alloc(128 * 16 * 4));   // all-to-all flags, 64B stride
    unsigned int* bar1 = (unsigned int*)(ws + alloc(128 * 16 * 4));
    // hs1 region sub-aliases (all dead before scan L1 writes hs1):
    ushort* hs1_0 = (ushort*)hs1reg;
    ushort* hs1_1 = (ushort*)(hs1reg + 16777216);
    ushort* hs1_2 = (ushort*)(hs1reg + 33554432);
    ushort* xn0   = (ushort*)(hs1reg + 0);           // xn: bn1 -> gemm L0
    ushort* xn1   = (ushort*)(hs1reg + 8388608);
    ushort* xn2   = (ushort*)(hs1reg + 16777216);
    ushort* WI0_0 = (ushort*)(hs1reg + 25165824);    // W_ih0: conv -> gemm L0
    ushort* WI0_1 = (ushort*)(hs1reg + 29360128);
    ushort* WI0_2 = (ushort*)(hs1reg + 33554432);
    ushort* WH0_0 = (ushort*)(hs1reg + 37748736);    // W_hh0: conv -> scan L0
    ushort* WH0_1 = (ushort*)(hs1reg + 41943040);
    ushort* WH0_2 = (ushort*)(hs1reg + 46137344);    // ends at 50331648 = region end
    ushort* WI1_0 = (ushort*)(hs1reg + 0);           // W_ih1: after xn dead -> gemm L1
    ushort* WI1_1 = (ushort*)(hs1reg + 8388608);
    ushort* WI1_2 = (ushort*)(hs1reg + 16777216);
    float*  ybuf  = (float*)xg;                      // 33.6 MB fp32, xg dead after scan L1

    hipMemsetAsync(st1, 0, 1024 * 4, stream);
    hipMemsetAsync(st2, 0, 2048 * 4, stream);
    hipMemsetAsync(bar0, 0, 128 * 16 * 4, stream);
    hipMemsetAsync(bar1, 0, 128 * 16 * 4, stream);

    // stage layer-0 weights (3-split)
    conv_split3_k<<<2048, 256, 0, stream>>>(w_ih0, WI0_0, WI0_1, WI0_2, 2097152 / 4);
    conv_split3_k<<<2048, 256, 0, stream>>>(w_hh0, WH0_0, WH0_1, WH0_2, 2097152 / 4);

    // BN1 + transpose to (T,B,V), 3-split
    bn1_stats_k<<<64, 256, 0, stream>>>(in_x, st1);
    bn1_final_k<<<2, 256, 0, stream>>>(st1, bn1g, bn1b, ac1);
    bn1_apply3_k<<<8192, 128, 0, stream>>>(in_x, ac1, xn0, xn1, xn2);

    // ---- layer 0 ----
    gemm6_k<<<dim3(16, 64, 2), 256, 0, stream>>>(xn0, xn1, xn2, WI0_0, WI0_1, WI0_2, xg, 512);
    ln_rows32_k<<<dim3(8192, 2), 256, 0, stream>>>(xg, lng0, lnb0);
    lstm_scan4_k<<<128, 256, 0, stream>>>(xg, WH0_0, WH0_1, WH0_2, lng0, lnb0,
                                          hb0, hb1, hb2, graw, hs0_0, hs0_1, hs0_2, bar0);

    // stage layer-1 weights (xn / WI0 regions now dead)
    conv_split3_k<<<4096, 256, 0, stream>>>(w_ih1, WI1_0, WI1_1, WI1_2, 4194304 / 4);
    conv_split3_k<<<2048, 256, 0, stream>>>(w_hh1, WH1_0, WH1_1, WH1_2, 2097152 / 4);

    // ---- layer 1 ----
    gemm6_k<<<dim3(16, 64, 2), 256, 0, stream>>>(hs0_0, hs0_1, hs0_2, WI1_0, WI1_1, WI1_2, xg, 1024);
    ln_rows32_k<<<dim3(8192, 2), 256, 0, stream>>>(xg, lng1, lnb1);
    lstm_scan4_k<<<128, 256, 0, stream>>>(xg, WH1_0, WH1_1, WH1_2, lng1, lnb1,
                                          hb0, hb1, hb2, graw, hs1_0, hs1_1, hs1_2, bar1);

    // BN2 -> y fp32 (B,T,2H); ybuf aliases dead xg
    bn2_stats3_k<<<128, 256, 0, stream>>>(hs1_0, hs1_1, hs1_2, st2);
    bn2_final_k<<<1, 256, 0, stream>>>(st2, bn2g, bn2b, ac2);
    bn2_apply3_k<<<8192, 256, 0, stream>>>(hs1_0, hs1_1, hs1_2, ac2, ybuf);

    // attention + output
    att_scores_k<<<8192, 64, 0, stream>>>(ybuf, w_om, b_om, u_om, sc);
    att_softmax_k<<<64, 128, 0, stream>>>(sc, al);
    att_pool_k<<<64, 256, 0, stream>>>(ybuf, al, pooled);
    out_gemv_k<<<64, 256, 0, stream>>>(pooled, Wf, out);
}

// Round 7
// 8828.733 us; speedup vs baseline: 1.3923x; 1.1193x over previous
//
#include <hip/hip_runtime.h>
#include <hip/hip_bf16.h>

// Problem dims: B=64, T=128, V=512, H=512, 4H=2048, 2H=1024, A=64, C+1=501
// ALL inputs fp32, output fp32.
// Precision (R3/R5): 3-way bf16 split + 6 MFMA products + fp32 xg/LN/pointwise
// -> absmax 2e-3 vs 1.02e-2 gate. DO NOT reduce splits/products.
// Sync evolution:
//   R5: acquire/release atomics -> buffer_inv/wbl2 PER POLL -> 41.5us/step.
//   R6: relaxed sc1 atomics for ALL data -> h loads bypass L1/L2, serialized
//       at MALL latency -> 32us/step, FETCH 348MB.
//   R7 (this): bulk data on the NORMAL cached path; coherence via ONE fence
//       pair per barrier (release->wbl2 before flag store, acquire->inv after
//       poll); only the 128 barrier flags are relaxed-sc1. W_hh lives in
//       REGISTERS (48 bf16x8/wave, 192 VGPRs) so per-step L2 inv costs no W
//       re-fetch.
// Workspace: ws_size = 256 MiB (R4); packed ~238 MiB via temporal aliasing.
#define LN_EPS 1e-5f

using bf16x8 = __attribute__((ext_vector_type(8))) short;
using f32x4  = __attribute__((ext_vector_type(4))) float;

__device__ __forceinline__ float bf2f(ushort u) {
    union { unsigned int i; float f; } v; v.i = ((unsigned int)u) << 16; return v.f;
}
__device__ __forceinline__ ushort f2bf(float f) {
    union { unsigned int i; float f; } v; v.f = f;
    unsigned int r = v.i + 0x7FFFu + ((v.i >> 16) & 1u);
    return (ushort)(r >> 16);
}
// 3-way split: x ~= a + b + c, residual ~2^-26|x|
__device__ __forceinline__ void split3(float x, ushort& a, ushort& b, ushort& c) {
    a = f2bf(x); float r = x - bf2f(a);
    b = f2bf(r); float r2 = r - bf2f(b);
    c = f2bf(r2);
}

// flag access: relaxed agent atomics (sc1, MALL-coherent, no cache maintenance)
__device__ __forceinline__ unsigned ld_flag(const unsigned* p) {
    return __hip_atomic_load(p, __ATOMIC_RELAXED, __HIP_MEMORY_SCOPE_AGENT);
}
__device__ __forceinline__ void st_flag(unsigned* p, unsigned v) {
    __hip_atomic_store(p, v, __ATOMIC_RELAXED, __HIP_MEMORY_SCOPE_AGENT);
}

__device__ __forceinline__ void blockReduceSum2(float& a, float& b, float* red) {
    #pragma unroll
    for (int off = 32; off > 0; off >>= 1) {
        a += __shfl_down(a, off, 64);
        b += __shfl_down(b, off, 64);
    }
    const int nw = blockDim.x >> 6;
    const int w = threadIdx.x >> 6;
    if ((threadIdx.x & 63) == 0) { red[2 * w] = a; red[2 * w + 1] = b; }
    __syncthreads();
    if (threadIdx.x == 0) {
        float sa = 0.f, sb = 0.f;
        for (int i = 0; i < nw; ++i) { sa += red[2 * i]; sb += red[2 * i + 1]; }
        red[10] = sa; red[11] = sb;
    }
    __syncthreads();
    a = red[10]; b = red[11];
    __syncthreads();
}

// ---------------- fp32 -> 3-way bf16 split staging ----------------
__global__ __launch_bounds__(256) void conv_split3_k(const float* __restrict__ src, ushort* __restrict__ d0,
                                                     ushort* __restrict__ d1, ushort* __restrict__ d2, int n4) {
    int i = blockIdx.x * 256 + threadIdx.x;
    if (i < n4) {
        float4 v = ((const float4*)src)[i];
        ushort4 a, b, c;
        split3(v.x, a.x, b.x, c.x); split3(v.y, a.y, b.y, c.y);
        split3(v.z, a.z, b.z, c.z); split3(v.w, a.w, b.w, c.w);
        ((ushort4*)d0)[i] = a; ((ushort4*)d1)[i] = b; ((ushort4*)d2)[i] = c;
    }
}

// ---------------- BatchNorm 1 ----------------
__global__ __launch_bounds__(256) void bn1_stats_k(const float* __restrict__ in, float* __restrict__ st) {
    int b = blockIdx.x, tid = threadIdx.x;
    float s10 = 0, s20 = 0, s11 = 0, s21 = 0;
    const float* p = in + (size_t)b * 128 * 512;
    for (int t = 0; t < 128; ++t) {
        float x0 = p[t * 512 + tid];
        float x1 = p[t * 512 + tid + 256];
        s10 += x0; s20 += x0 * x0; s11 += x1; s21 += x1 * x1;
    }
    atomicAdd(&st[tid], s10);       atomicAdd(&st[512 + tid], s20);
    atomicAdd(&st[tid + 256], s11); atomicAdd(&st[512 + tid + 256], s21);
}

__global__ void bn1_final_k(const float* __restrict__ st, const float* __restrict__ g,
                            const float* __restrict__ bb, float* __restrict__ ac) {
    int d = threadIdx.x + blockIdx.x * 256;
    if (d < 512) {
        float m = st[d] * (1.f / 8192.f);
        float v = st[512 + d] * (1.f / 8192.f) - m * m;
        float a = g[d] * rsqrtf(v + LN_EPS);
        ac[d] = a; ac[512 + d] = bb[d] - m * a;
    }
}

// xn[t*64+b][d] 3-split with (b,t)->(t,b) transpose
__global__ __launch_bounds__(128) void bn1_apply3_k(const float* __restrict__ in, const float* __restrict__ ac,
                                                    ushort* __restrict__ x0, ushort* __restrict__ x1,
                                                    ushort* __restrict__ x2) {
    int beta = blockIdx.x;           // t*64+b
    int t = beta >> 6, b = beta & 63;
    const float* src = in + ((size_t)b * 128 + t) * 512;
    #pragma unroll
    for (int k = 0; k < 4; ++k) {
        int d = threadIdx.x + 128 * k;
        ushort a, m, l;
        split3(ac[d] * src[d] + ac[512 + d], a, m, l);
        x0[(size_t)beta * 512 + d] = a;
        x1[(size_t)beta * 512 + d] = m;
        x2[(size_t)beta * 512 + d] = l;
    }
}

// ---------------- xg GEMM (3-split, 6 products): C[dir][m][n] fp32 ----------------
__global__ __launch_bounds__(256) void gemm6_k(const ushort* __restrict__ A0, const ushort* __restrict__ A1,
                                               const ushort* __restrict__ A2,
                                               const ushort* __restrict__ W0, const ushort* __restrict__ W1,
                                               const ushort* __restrict__ W2,
                                               float* __restrict__ C, int K) {
    const int dir = blockIdx.z;
    const ushort* Wp0 = W0 + (size_t)dir * 2048 * K;
    const ushort* Wp1 = W1 + (size_t)dir * 2048 * K;
    const ushort* Wp2 = W2 + (size_t)dir * 2048 * K;
    const int wave = threadIdx.x >> 6, lane = threadIdx.x & 63;
    const int l15 = lane & 15, kq = lane >> 4;
    const int m0 = blockIdx.y * 128 + (wave >> 1) * 64;
    const int n0 = blockIdx.x * 128 + (wave & 1) * 64;
    f32x4 acc[4][4];
    #pragma unroll
    for (int i = 0; i < 4; ++i)
        #pragma unroll
        for (int j = 0; j < 4; ++j) acc[i][j] = (f32x4){0.f, 0.f, 0.f, 0.f};
    for (int k0 = 0; k0 < K; k0 += 32) {
        bf16x8 a0[4], a1[4], a2[4], b0[4], b1[4], b2[4];
        #pragma unroll
        for (int i = 0; i < 4; ++i) {
            size_t o = (size_t)(m0 + i * 16 + l15) * K + k0 + kq * 8;
            a0[i] = *(const bf16x8*)(A0 + o);
            a1[i] = *(const bf16x8*)(A1 + o);
            a2[i] = *(const bf16x8*)(A2 + o);
        }
        #pragma unroll
        for (int j = 0; j < 4; ++j) {
            size_t o = (size_t)(n0 + j * 16 + l15) * K + k0 + kq * 8;
            b0[j] = *(const bf16x8*)(Wp0 + o);
            b1[j] = *(const bf16x8*)(Wp1 + o);
            b2[j] = *(const bf16x8*)(Wp2 + o);
        }
        #pragma unroll
        for (int i = 0; i < 4; ++i)
            #pragma unroll
            for (int j = 0; j < 4; ++j) {
                acc[i][j] = __builtin_amdgcn_mfma_f32_16x16x32_bf16(a2[i], b0[j], acc[i][j], 0, 0, 0);
                acc[i][j] = __builtin_amdgcn_mfma_f32_16x16x32_bf16(a1[i], b1[j], acc[i][j], 0, 0, 0);
                acc[i][j] = __builtin_amdgcn_mfma_f32_16x16x32_bf16(a0[i], b2[j], acc[i][j], 0, 0, 0);
                acc[i][j] = __builtin_amdgcn_mfma_f32_16x16x32_bf16(a1[i], b0[j], acc[i][j], 0, 0, 0);
                acc[i][j] = __builtin_amdgcn_mfma_f32_16x16x32_bf16(a0[i], b1[j], acc[i][j], 0, 0, 0);
                acc[i][j] = __builtin_amdgcn_mfma_f32_16x16x32_bf16(a0[i], b0[j], acc[i][j], 0, 0, 0);
            }
    }
    #pragma unroll
    for (int i = 0; i < 4; ++i)
        #pragma unroll
        for (int j = 0; j < 4; ++j)
            #pragma unroll
            for (int r = 0; r < 4; ++r)
                C[(size_t)dir * 8192 * 2048 + (size_t)(m0 + i * 16 + kq * 4 + r) * 2048 + n0 + j * 16 + l15]
                    = acc[i][j][r];
}

// ---------------- in-place row LayerNorm fp32, rows of 2048; grid (8192,2) ----------------
__global__ __launch_bounds__(256) void ln_rows32_k(float* __restrict__ X, const float* __restrict__ lng,
                                                   const float* __restrict__ lnb) {
    __shared__ float red[12];
    const int dir = blockIdx.y;
    float* row = X + ((size_t)dir * 8192 + blockIdx.x) * 2048;
    const float* g = lng + dir * 4608;
    const float* bb = lnb + dir * 4608;
    const int tid = threadIdx.x;
    float4 v0 = ((const float4*)row)[tid], v1 = ((const float4*)row)[tid + 256];
    float s1 = v0.x + v0.y + v0.z + v0.w + v1.x + v1.y + v1.z + v1.w;
    float s2 = v0.x * v0.x + v0.y * v0.y + v0.z * v0.z + v0.w * v0.w
             + v1.x * v1.x + v1.y * v1.y + v1.z * v1.z + v1.w * v1.w;
    blockReduceSum2(s1, s2, red);
    float m = s1 * (1.f / 2048.f);
    float rs = rsqrtf(s2 * (1.f / 2048.f) - m * m + LN_EPS);
    float4 g0 = ((const float4*)g)[tid],  g1 = ((const float4*)g)[tid + 256];
    float4 b0 = ((const float4*)bb)[tid], b1 = ((const float4*)bb)[tid + 256];
    float4 o0, o1;
    o0.x = (v0.x - m) * rs * g0.x + b0.x; o0.y = (v0.y - m) * rs * g0.y + b0.y;
    o0.z = (v0.z - m) * rs * g0.z + b0.z; o0.w = (v0.w - m) * rs * g0.w + b0.w;
    o1.x = (v1.x - m) * rs * g1.x + b1.x; o1.y = (v1.y - m) * rs * g1.y + b1.y;
    o1.z = (v1.z - m) * rs * g1.z + b1.z; o1.w = (v1.w - m) * rs * g1.w + b1.w;
    ((float4*)row)[tid] = o0;
    ((float4*)row)[tid + 256] = o1;
}

// ---------------- grid barrier: one fence pair per crossing ----------------
// Data path is NORMAL cached loads/stores. Release fence (buffer_wbl2) pushes
// this XCD's dirty L2 to MALL before the flag store; after all flags are seen,
// each wave's acquire fence (buffer_inv) drops stale L1/L2 lines.
__device__ __forceinline__ void gbar3(unsigned int* flags, unsigned int e) {
    __builtin_amdgcn_s_waitcnt(0);
    __syncthreads();
    if (threadIdx.x == 0) {
        __builtin_amdgcn_fence(__ATOMIC_RELEASE, "agent");      // wbl2
        st_flag(&flags[blockIdx.x * 16], e);
    }
    if (threadIdx.x < 128) {
        while (ld_flag(&flags[threadIdx.x * 16]) < e)
            __builtin_amdgcn_s_sleep(2);
    }
    __syncthreads();
    __builtin_amdgcn_fence(__ATOMIC_ACQUIRE, "agent");          // inv (per wave)
}

// ---------------- LSTM scan, one layer, both dirs; 128x256 ----------------
// Phase A: block beta -> (dir=beta>>6) gate cols (beta&63)*32..+31, all 64 rows.
//   W_hh fragments preloaded to REGISTERS (48 bf16x8/wave); h via normal cached
//   loads; gates via normal stores.
// Phase B: block beta -> row (dir, b=beta&63); thread owns gate cols 2t,2t+1.
__global__ __launch_bounds__(256, 1) void lstm_scan5_k(
    const float* __restrict__ xg,
    const ushort* __restrict__ w0, const ushort* __restrict__ w1, const ushort* __restrict__ w2,
    const float* __restrict__ lng, const float* __restrict__ lnb,
    ushort* __restrict__ hb0, ushort* __restrict__ hb1, ushort* __restrict__ hb2,
    float* __restrict__ graw,
    ushort* __restrict__ hs0, ushort* __restrict__ hs1, ushort* __restrict__ hs2,
    unsigned int* __restrict__ flags) {
    __shared__ float red[12];
    const int beta = blockIdx.x, tid = threadIdx.x;
    const int dirB = beta >> 6, bB = beta & 63;
    const int wave = tid >> 6, lane = tid & 63, l15 = lane & 15, kq = lane >> 4;
    const size_t hro = (size_t)(dirB * 64 + bB) * 512;
    // zero own h row (normal stores; first barrier's release publishes them)
    ((unsigned*)(hb0 + hro))[tid] = 0u;
    ((unsigned*)(hb1 + hro))[tid] = 0u;
    ((unsigned*)(hb2 + hro))[tid] = 0u;
    float c0 = 0.f, c1 = 0.f;
    const float* g_hh = lng + dirB * 4608 + 2048;
    const float* b_hh = lnb + dirB * 4608 + 2048;
    const float2 gcv = ((const float2*)(lng + dirB * 4608 + 4096))[tid];
    const float2 bcv = ((const float2*)(lnb + dirB * 4608 + 4096))[tid];
    // phase-A tile assignment: 4 waves cover 64 rows x 32 cols
    const int jj = wave >> 1, ip = wave & 1;
    const int nn = bB * 32 + jj * 16;
    const ushort* h0d = hb0 + (size_t)dirB * 64 * 512;
    const ushort* h1d = hb1 + (size_t)dirB * 64 * 512;
    const ushort* h2d = hb2 + (size_t)dirB * 64 * 512;
    float* gr = graw + dirB * 64 * 2048;
    // ---- preload W_hh fragments into registers: 16 k-tiles x 3 planes ----
    bf16x8 wr[16][3];
    {
        const ushort* w0d = w0 + (size_t)dirB * 2048 * 512;
        const ushort* w1d = w1 + (size_t)dirB * 2048 * 512;
        const ushort* w2d = w2 + (size_t)dirB * 2048 * 512;
        #pragma unroll
        for (int kt = 0; kt < 16; ++kt) {
            size_t wo = (size_t)(nn + l15) * 512 + kt * 32 + kq * 8;
            wr[kt][0] = *(const bf16x8*)(w0d + wo);
            wr[kt][1] = *(const bf16x8*)(w1d + wo);
            wr[kt][2] = *(const bf16x8*)(w2d + wo);
        }
    }
    unsigned int e = 0;
    gbar3(flags, ++e);
    for (int s = 0; s < 128; ++s) {
        // -------- phase A: 6-product MFMA, W in regs, h cached --------
        {
            f32x4 acc[2];
            acc[0] = (f32x4){0.f, 0.f, 0.f, 0.f};
            acc[1] = (f32x4){0.f, 0.f, 0.f, 0.f};
            #pragma unroll
            for (int kt = 0; kt < 16; ++kt) {
                #pragma unroll
                for (int ii = 0; ii < 2; ++ii) {
                    size_t ho = (size_t)(ip * 32 + ii * 16 + l15) * 512 + kt * 32 + kq * 8;
                    bf16x8 a0 = *(const bf16x8*)(h0d + ho);
                    bf16x8 a1 = *(const bf16x8*)(h1d + ho);
                    bf16x8 a2 = *(const bf16x8*)(h2d + ho);
                    acc[ii] = __builtin_amdgcn_mfma_f32_16x16x32_bf16(a2, wr[kt][0], acc[ii], 0, 0, 0);
                    acc[ii] = __builtin_amdgcn_mfma_f32_16x16x32_bf16(a1, wr[kt][1], acc[ii], 0, 0, 0);
                    acc[ii] = __builtin_amdgcn_mfma_f32_16x16x32_bf16(a0, wr[kt][2], acc[ii], 0, 0, 0);
                    acc[ii] = __builtin_amdgcn_mfma_f32_16x16x32_bf16(a1, wr[kt][0], acc[ii], 0, 0, 0);
                    acc[ii] = __builtin_amdgcn_mfma_f32_16x16x32_bf16(a0, wr[kt][1], acc[ii], 0, 0, 0);
                    acc[ii] = __builtin_amdgcn_mfma_f32_16x16x32_bf16(a0, wr[kt][0], acc[ii], 0, 0, 0);
                }
            }
            #pragma unroll
            for (int ii = 0; ii < 2; ++ii)
                #pragma unroll
                for (int r = 0; r < 4; ++r)
                    gr[(ip * 32 + ii * 16 + kq * 4 + r) * 2048 + nn + l15] = acc[ii][r];
        }
        gbar3(flags, ++e);
        // -------- phase B: own row; thread owns gate cols 2t, 2t+1 --------
        {
            const int time = dirB ? (127 - s) : s;
            const float2* grow = (const float2*)(gr + bB * 2048);
            float v[8];
            #pragma unroll
            for (int j = 0; j < 4; ++j) {
                float2 g2 = grow[j * 256 + tid];
                v[2 * j] = g2.x; v[2 * j + 1] = g2.y;
            }
            float s1 = 0.f, s2 = 0.f;
            #pragma unroll
            for (int k = 0; k < 8; ++k) { s1 += v[k]; s2 += v[k] * v[k]; }
            blockReduceSum2(s1, s2, red);
            float mu = s1 * (1.f / 2048.f);
            float rs = rsqrtf(s2 * (1.f / 2048.f) - mu * mu + LN_EPS);
            const float2* xr = (const float2*)(xg + ((size_t)dirB * 8192 + (size_t)time * 64 + bB) * 2048);
            float nv[8];
            #pragma unroll
            for (int j = 0; j < 4; ++j) {
                float2 xv = xr[tid + 256 * j];
                float2 gh = ((const float2*)g_hh)[tid + 256 * j];
                float2 bh = ((const float2*)b_hh)[tid + 256 * j];
                nv[2 * j]     = xv.x + (v[2 * j]     - mu) * rs * gh.x + bh.x;
                nv[2 * j + 1] = xv.y + (v[2 * j + 1] - mu) * rs * gh.y + bh.y;
            }
            float si0 = 1.f / (1.f + expf(-nv[0])), si1 = 1.f / (1.f + expf(-nv[1]));
            float sf0 = 1.f / (1.f + expf(-nv[2])), sf1 = 1.f / (1.f + expf(-nv[3]));
            c0 = sf0 * c0 + si0 * tanhf(nv[4]);
            c1 = sf1 * c1 + si1 * tanhf(nv[5]);
            float t1 = c0 + c1, t2 = c0 * c0 + c1 * c1;
            blockReduceSum2(t1, t2, red);
            float mc = t1 * (1.f / 512.f);
            float rc = rsqrtf(t2 * (1.f / 512.f) - mc * mc + LN_EPS);
            float so0 = 1.f / (1.f + expf(-nv[6])), so1 = 1.f / (1.f + expf(-nv[7]));
            float h0v = so0 * tanhf((c0 - mc) * rc * gcv.x + bcv.x);
            float h1v = so1 * tanhf((c1 - mc) * rc * gcv.y + bcv.y);
            ushort a0, m0, l0, a1, m1, l1;
            split3(h0v, a0, m0, l0);
            split3(h1v, a1, m1, l1);
            unsigned p0 = (unsigned)a0 | ((unsigned)a1 << 16);
            unsigned p1 = (unsigned)m0 | ((unsigned)m1 << 16);
            unsigned p2 = (unsigned)l0 | ((unsigned)l1 << 16);
            ((unsigned*)(hb0 + hro))[tid] = p0;
            ((unsigned*)(hb1 + hro))[tid] = p1;
            ((unsigned*)(hb2 + hro))[tid] = p2;
            size_t oro = ((size_t)time * 64 + bB) * 1024 + dirB * 512;
            ((unsigned*)(hs0 + oro))[tid] = p0;
            ((unsigned*)(hs1 + oro))[tid] = p1;
            ((unsigned*)(hs2 + oro))[tid] = p2;
        }
        gbar3(flags, ++e);
    }
}

// ---------------- BatchNorm 2 (reads 3-split hs) ----------------
__global__ __launch_bounds__(256) void bn2_stats3_k(const ushort* __restrict__ h0, const ushort* __restrict__ h1,
                                                    const ushort* __restrict__ h2, float* __restrict__ st) {
    int t = blockIdx.x, tid = threadIdx.x;
    float s1[4] = {0, 0, 0, 0}, s2[4] = {0, 0, 0, 0};
    size_t base = (size_t)t * 64 * 1024;
    for (int b = 0; b < 64; ++b) {
        #pragma unroll
        for (int k = 0; k < 4; ++k) {
            size_t o = base + b * 1024 + tid + 256 * k;
            float x = bf2f(h0[o]) + bf2f(h1[o]) + bf2f(h2[o]);
            s1[k] += x; s2[k] += x * x;
        }
    }
    #pragma unroll
    for (int k = 0; k < 4; ++k) {
        atomicAdd(&st[tid + 256 * k], s1[k]);
        atomicAdd(&st[1024 + tid + 256 * k], s2[k]);
    }
}

__global__ void bn2_final_k(const float* __restrict__ st, const float* __restrict__ g,
                            const float* __restrict__ bb, float* __restrict__ ac) {
    #pragma unroll
    for (int k = 0; k < 4; ++k) {
        int h = threadIdx.x + 256 * k;
        float m = st[h] * (1.f / 8192.f);
        float v = st[1024 + h] * (1.f / 8192.f) - m * m;
        float a = g[h] * rsqrtf(v + LN_EPS);
        ac[h] = a; ac[1024 + h] = bb[h] - m * a;
    }
}

__global__ __launch_bounds__(256) void bn2_apply3_k(const ushort* __restrict__ h0, const ushort* __restrict__ h1,
                                                    const ushort* __restrict__ h2, const float* __restrict__ ac,
                                                    float* __restrict__ y) {
    int beta = blockIdx.x;        // b*128+t
    int b = beta >> 7, t = beta & 127;
    size_t so = ((size_t)t * 64 + b) * 1024;
    float* dst = y + (size_t)beta * 1024;
    #pragma unroll
    for (int k = 0; k < 4; ++k) {
        int h = threadIdx.x + 256 * k;
        float x = bf2f(h0[so + h]) + bf2f(h1[so + h]) + bf2f(h2[so + h]);
        dst[h] = ac[h] * x + ac[1024 + h];
    }
}

// ---------------- attention (fp32) ----------------
__global__ __launch_bounds__(64) void att_scores_k(const float* __restrict__ y, const float* __restrict__ wo,
                                                   const float* __restrict__ bo, const float* __restrict__ uo,
                                                   float* __restrict__ sc) {
    int row = blockIdx.x;     // b*128+t
    int a = threadIdx.x;
    const float* yr = y + (size_t)row * 1024;
    float acc = bo[a];
    for (int h = 0; h < 1024; h += 4) {
        float4 yv = *(const float4*)(yr + h);
        acc += yv.x * wo[(h + 0) * 64 + a];
        acc += yv.y * wo[(h + 1) * 64 + a];
        acc += yv.z * wo[(h + 2) * 64 + a];
        acc += yv.w * wo[(h + 3) * 64 + a];
    }
    float p = tanhf(acc) * uo[a];
    #pragma unroll
    for (int off = 32; off > 0; off >>= 1) p += __shfl_down(p, off, 64);
    if (a == 0) sc[row] = p;
}

__global__ __launch_bounds__(128) void att_softmax_k(const float* __restrict__ sc, float* __restrict__ al) {
    __shared__ float red[8];
    int b = blockIdx.x, t = threadIdx.x;
    int lane = t & 63, w = t >> 6;
    float v = sc[b * 128 + t];
    float m = v;
    #pragma unroll
    for (int off = 32; off > 0; off >>= 1) m = fmaxf(m, __shfl_down(m, off, 64));
    if (lane == 0) red[w] = m;
    __syncthreads();
    m = fmaxf(red[0], red[1]);
    float e = expf(v - m);
    float sum = e;
    #pragma unroll
    for (int off = 32; off > 0; off >>= 1) sum += __shfl_down(sum, off, 64);
    if (lane == 0) red[2 + w] = sum;
    __syncthreads();
    sum = red[2] + red[3];
    al[b * 128 + t] = e / sum;
}

__global__ __launch_bounds__(256) void att_pool_k(const float* __restrict__ y, const float* __restrict__ al,
                                                  float* __restrict__ pooled) {
    int b = blockIdx.x, tid = threadIdx.x;
    float acc[4] = {0, 0, 0, 0};
    const float* yb = y + (size_t)b * 128 * 1024;
    for (int t = 0; t < 128; ++t) {
        float a = al[b * 128 + t];
        #pragma unroll
        for (int k = 0; k < 4; ++k) acc[k] += a * yb[t * 1024 + tid + 256 * k];
    }
    #pragma unroll
    for (int k = 0; k < 4; ++k) pooled[b * 1024 + tid + 256 * k] = acc[k];
}

__global__ __launch_bounds__(256) void out_gemv_k(const float* __restrict__ pooled, const float* __restrict__ W,
                                                  float* __restrict__ out) {
    int b = blockIdx.x, tid = threadIdx.x;
    const float* pb = pooled + b * 1024;
    #pragma unroll
    for (int rep = 0; rep < 2; ++rep) {
        int c = tid + rep * 256;
        if (c < 501) {
            float acc = W[(size_t)1024 * 501 + c];   // bias row (emb padded with 1)
            for (int h = 0; h < 1024; ++h) acc += pb[h] * W[(size_t)h * 501 + c];
            out[b * 501 + c] = acc;
        }
    }
}

extern "C" void kernel_launch(void* const* d_in, const int* in_sizes, int n_in,
                              void* d_out, int out_size, void* d_ws, size_t ws_size,
                              hipStream_t stream) {
    (void)in_sizes; (void)n_in; (void)out_size; (void)ws_size;
    const float* in_x  = (const float*)d_in[0];
    const float* bn1g  = (const float*)d_in[1];
    const float* bn1b  = (const float*)d_in[2];
    const float* bn2g  = (const float*)d_in[3];
    const float* bn2b  = (const float*)d_in[4];
    const float* w_ih0 = (const float*)d_in[5];
    const float* w_hh0 = (const float*)d_in[6];
    const float* lng0  = (const float*)d_in[7];
    const float* lnb0  = (const float*)d_in[8];
    const float* w_ih1 = (const float*)d_in[9];
    const float* w_hh1 = (const float*)d_in[10];
    const float* lng1  = (const float*)d_in[11];
    const float* lnb1  = (const float*)d_in[12];
    const float* w_om  = (const float*)d_in[13];
    const float* b_om  = (const float*)d_in[14];
    const float* u_om  = (const float*)d_in[15];
    const float* Wf    = (const float*)d_in[16];
    float* out = (float*)d_out;

    // ---- workspace: ~238 MiB of the 256 MiB budget ----
    char* ws = (char*)d_ws;
    size_t off = 0;
    auto alloc = [&](size_t bytes) { size_t o = off; off += (bytes + 255) & ~(size_t)255; return o; };
    float*  xg     = (float*)(ws + alloc(2ull * 8192 * 2048 * 4));    // 134.2 MB; ybuf aliases later
    ushort* hs0_0  = (ushort*)(ws + alloc(8192ull * 1024 * 2));       // hs0 3-split, 50.3 MB
    ushort* hs0_1  = (ushort*)(ws + alloc(8192ull * 1024 * 2));
    ushort* hs0_2  = (ushort*)(ws + alloc(8192ull * 1024 * 2));
    char*   hs1reg = ws + alloc(3ull * 8192 * 1024 * 2);              // hs1 region, 50.3 MB (aliased below)
    ushort* WH1_0  = (ushort*)(ws + alloc(2ull * 2048 * 512 * 2));    // W_hh1 3-split (live during scan L1)
    ushort* WH1_1  = (ushort*)(ws + alloc(2ull * 2048 * 512 * 2));
    ushort* WH1_2  = (ushort*)(ws + alloc(2ull * 2048 * 512 * 2));
    float*  graw   = (float*)(ws + alloc(2ull * 64 * 2048 * 4));      // 1 MB
    ushort* hb0    = (ushort*)(ws + alloc(2ull * 64 * 512 * 2));
    ushort* hb1    = (ushort*)(ws + alloc(2ull * 64 * 512 * 2));
    ushort* hb2    = (ushort*)(ws + alloc(2ull * 64 * 512 * 2));
    float*  st1    = (float*)(ws + alloc(1024 * 4));
    float*  ac1    = (float*)(ws + alloc(1024 * 4));
    float*  st2    = (float*)(ws + alloc(2048 * 4));
    float*  ac2    = (float*)(ws + alloc(2048 * 4));
    float*  sc     = (float*)(ws + alloc(8192 * 4));
    float*  al     = (float*)(ws + alloc(8192 * 4));
    float*  pooled = (float*)(ws + alloc(64ull * 1024 * 4));
    unsigned int* bar0 = (unsigned int*)(ws + alloc(128 * 16 * 4));   // all-to-all flags, 64B stride
    unsigned int* bar1 = (unsigned int*)(ws + alloc(128 * 16 * 4));
    // hs1 region sub-aliases (all dead before scan L1 writes hs1):
    ushort* hs1_0 = (ushort*)hs1reg;
    ushort* hs1_1 = (ushort*)(hs1reg + 16777216);
    ushort* hs1_2 = (ushort*)(hs1reg + 33554432);
    ushort* xn0   = (ushort*)(hs1reg + 0);           // xn: bn1 -> gemm L0
    ushort* xn1   = (ushort*)(hs1reg + 8388608);
    ushort* xn2   = (ushort*)(hs1reg + 16777216);
    ushort* WI0_0 = (ushort*)(hs1reg + 25165824);    // W_ih0: conv -> gemm L0
    ushort* WI0_1 = (ushort*)(hs1reg + 29360128);
    ushort* WI0_2 = (ushort*)(hs1reg + 33554432);
    ushort* WH0_0 = (ushort*)(hs1reg + 37748736);    // W_hh0: conv -> scan L0
    ushort* WH0_1 = (ushort*)(hs1reg + 41943040);
    ushort* WH0_2 = (ushort*)(hs1reg + 46137344);    // ends at 50331648 = region end
    ushort* WI1_0 = (ushort*)(hs1reg + 0);           // W_ih1: after xn dead -> gemm L1
    ushort* WI1_1 = (ushort*)(hs1reg + 8388608);
    ushort* WI1_2 = (ushort*)(hs1reg + 16777216);
    float*  ybuf  = (float*)xg;                      // 33.6 MB fp32, xg dead after scan L1

    hipMemsetAsync(st1, 0, 1024 * 4, stream);
    hipMemsetAsync(st2, 0, 2048 * 4, stream);
    hipMemsetAsync(bar0, 0, 128 * 16 * 4, stream);
    hipMemsetAsync(bar1, 0, 128 * 16 * 4, stream);

    // stage layer-0 weights (3-split)
    conv_split3_k<<<2048, 256, 0, stream>>>(w_ih0, WI0_0, WI0_1, WI0_2, 2097152 / 4);
    conv_split3_k<<<2048, 256, 0, stream>>>(w_hh0, WH0_0, WH0_1, WH0_2, 2097152 / 4);

    // BN1 + transpose to (T,B,V), 3-split
    bn1_stats_k<<<64, 256, 0, stream>>>(in_x, st1);
    bn1_final_k<<<2, 256, 0, stream>>>(st1, bn1g, bn1b, ac1);
    bn1_apply3_k<<<8192, 128, 0, stream>>>(in_x, ac1, xn0, xn1, xn2);

    // ---- layer 0 ----
    gemm6_k<<<dim3(16, 64, 2), 256, 0, stream>>>(xn0, xn1, xn2, WI0_0, WI0_1, WI0_2, xg, 512);
    ln_rows32_k<<<dim3(8192, 2), 256, 0, stream>>>(xg, lng0, lnb0);
    lstm_scan5_k<<<128, 256, 0, stream>>>(xg, WH0_0, WH0_1, WH0_2, lng0, lnb0,
                                          hb0, hb1, hb2, graw, hs0_0, hs0_1, hs0_2, bar0);

    // stage layer-1 weights (xn / WI0 regions now dead)
    conv_split3_k<<<4096, 256, 0, stream>>>(w_ih1, WI1_0, WI1_1, WI1_2, 4194304 / 4);
    conv_split3_k<<<2048, 256, 0, stream>>>(w_hh1, WH1_0, WH1_1, WH1_2, 2097152 / 4);

    // ---- layer 1 ----
    gemm6_k<<<dim3(16, 64, 2), 256, 0, stream>>>(hs0_0, hs0_1, hs0_2, WI1_0, WI1_1, WI1_2, xg, 1024);
    ln_rows32_k<<<dim3(8192, 2), 256, 0, stream>>>(xg, lng1, lnb1);
    lstm_scan5_k<<<128, 256, 0, stream>>>(xg, WH1_0, WH1_1, WH1_2, lng1, lnb1,
                                          hb0, hb1, hb2, graw, hs1_0, hs1_1, hs1_2, bar1);

    // BN2 -> y fp32 (B,T,2H); ybuf aliases dead xg
    bn2_stats3_k<<<128, 256, 0, stream>>>(hs1_0, hs1_1, hs1_2, st2);
    bn2_final_k<<<1, 256, 0, stream>>>(st2, bn2g, bn2b, ac2);
    bn2_apply3_k<<<8192, 256, 0, stream>>>(hs1_0, hs1_1, hs1_2, ac2, ybuf);

    // attention + output
    att_scores_k<<<8192, 64, 0, stream>>>(ybuf, w_om, b_om, u_om, sc);
    att_softmax_k<<<64, 128, 0, stream>>>(sc, al);
    att_pool_k<<<64, 256, 0, stream>>>(ybuf, al, pooled);
    out_gemv_k<<<64, 256, 0, stream>>>(pooled, Wf, out);
}

// Round 8
// 7783.212 us; speedup vs baseline: 1.5793x; 1.1343x over previous
//
#include <hip/hip_runtime.h>
#include <hip/hip_bf16.h>

// Problem dims: B=64, T=128, V=512, H=512, 4H=2048, 2H=1024, A=64, C+1=501
// ALL inputs fp32, output fp32.
// Precision (R3/R5): 3-way bf16 split + 6 MFMA products + fp32 xg/LN/pointwise
// -> absmax 2e-3 vs 1.02e-2 gate. DO NOT reduce splits/products.
// Sync evolution (per-step cost of the 256-step recurrence):
//   R5 acquire/release per poll (inv+wbl2 each): 41.5us/step
//   R6 sc1 atomics for ALL data (h loads serialized at MALL): 32us/step
//   R7 cached data + 1 wbl2 + 1 inv per barrier: 28us/step (barriers ~25us)
//   R8 (this): cross-block STORES write-through sc1 (release = vmcnt wait,
//       NO wbl2); phase-B gate reads via sc1 u64 (mid-step barrier needs NO
//       inv); ONE buffer_inv per step (before cached h reads); per-dir flags;
//       xg prefetched during phase A.
// Workspace: ws_size = 256 MiB (R4); packed ~238 MiB via temporal aliasing.
#define LN_EPS 1e-5f

using bf16x8 = __attribute__((ext_vector_type(8))) short;
using f32x4  = __attribute__((ext_vector_type(4))) float;

__device__ __forceinline__ float bf2f(ushort u) {
    union { unsigned int i; float f; } v; v.i = ((unsigned int)u) << 16; return v.f;
}
__device__ __forceinline__ ushort f2bf(float f) {
    union { unsigned int i; float f; } v; v.f = f;
    unsigned int r = v.i + 0x7FFFu + ((v.i >> 16) & 1u);
    return (ushort)(r >> 16);
}
// 3-way split: x ~= a + b + c, residual ~2^-26|x|
__device__ __forceinline__ void split3(float x, ushort& a, ushort& b, ushort& c) {
    a = f2bf(x); float r = x - bf2f(a);
    b = f2bf(r); float r2 = r - bf2f(b);
    c = f2bf(r2);
}

// relaxed agent atomics -> plain sc1 (MALL-coherent, no cache maintenance)
__device__ __forceinline__ unsigned ld_flag(const unsigned* p) {
    return __hip_atomic_load(p, __ATOMIC_RELAXED, __HIP_MEMORY_SCOPE_AGENT);
}
__device__ __forceinline__ void st_flag(unsigned* p, unsigned v) {
    __hip_atomic_store(p, v, __ATOMIC_RELAXED, __HIP_MEMORY_SCOPE_AGENT);
}
__device__ __forceinline__ unsigned long long ld_u64_c(const void* p) {
    return __hip_atomic_load((const unsigned long long*)p, __ATOMIC_RELAXED, __HIP_MEMORY_SCOPE_AGENT);
}
__device__ __forceinline__ void st_u32_c(void* p, unsigned v) {
    __hip_atomic_store((unsigned*)p, v, __ATOMIC_RELAXED, __HIP_MEMORY_SCOPE_AGENT);
}
__device__ __forceinline__ void st_f32_c(void* p, float v) {
    union { unsigned u; float f; } c; c.f = v; st_u32_c(p, c.u);
}

__device__ __forceinline__ void blockReduceSum2(float& a, float& b, float* red) {
    #pragma unroll
    for (int off = 32; off > 0; off >>= 1) {
        a += __shfl_down(a, off, 64);
        b += __shfl_down(b, off, 64);
    }
    const int nw = blockDim.x >> 6;
    const int w = threadIdx.x >> 6;
    if ((threadIdx.x & 63) == 0) { red[2 * w] = a; red[2 * w + 1] = b; }
    __syncthreads();
    if (threadIdx.x == 0) {
        float sa = 0.f, sb = 0.f;
        for (int i = 0; i < nw; ++i) { sa += red[2 * i]; sb += red[2 * i + 1]; }
        red[10] = sa; red[11] = sb;
    }
    __syncthreads();
    a = red[10]; b = red[11];
    __syncthreads();
}

// ---------------- fp32 -> 3-way bf16 split staging ----------------
__global__ __launch_bounds__(256) void conv_split3_k(const float* __restrict__ src, ushort* __restrict__ d0,
                                                     ushort* __restrict__ d1, ushort* __restrict__ d2, int n4) {
    int i = blockIdx.x * 256 + threadIdx.x;
    if (i < n4) {
        float4 v = ((const float4*)src)[i];
        ushort4 a, b, c;
        split3(v.x, a.x, b.x, c.x); split3(v.y, a.y, b.y, c.y);
        split3(v.z, a.z, b.z, c.z); split3(v.w, a.w, b.w, c.w);
        ((ushort4*)d0)[i] = a; ((ushort4*)d1)[i] = b; ((ushort4*)d2)[i] = c;
    }
}

// ---------------- BatchNorm 1 ----------------
__global__ __launch_bounds__(256) void bn1_stats_k(const float* __restrict__ in, float* __restrict__ st) {
    int b = blockIdx.x, tid = threadIdx.x;
    float s10 = 0, s20 = 0, s11 = 0, s21 = 0;
    const float* p = in + (size_t)b * 128 * 512;
    for (int t = 0; t < 128; ++t) {
        float x0 = p[t * 512 + tid];
        float x1 = p[t * 512 + tid + 256];
        s10 += x0; s20 += x0 * x0; s11 += x1; s21 += x1 * x1;
    }
    atomicAdd(&st[tid], s10);       atomicAdd(&st[512 + tid], s20);
    atomicAdd(&st[tid + 256], s11); atomicAdd(&st[512 + tid + 256], s21);
}

__global__ void bn1_final_k(const float* __restrict__ st, const float* __restrict__ g,
                            const float* __restrict__ bb, float* __restrict__ ac) {
    int d = threadIdx.x + blockIdx.x * 256;
    if (d < 512) {
        float m = st[d] * (1.f / 8192.f);
        float v = st[512 + d] * (1.f / 8192.f) - m * m;
        float a = g[d] * rsqrtf(v + LN_EPS);
        ac[d] = a; ac[512 + d] = bb[d] - m * a;
    }
}

// xn[t*64+b][d] 3-split with (b,t)->(t,b) transpose
__global__ __launch_bounds__(128) void bn1_apply3_k(const float* __restrict__ in, const float* __restrict__ ac,
                                                    ushort* __restrict__ x0, ushort* __restrict__ x1,
                                                    ushort* __restrict__ x2) {
    int beta = blockIdx.x;           // t*64+b
    int t = beta >> 6, b = beta & 63;
    const float* src = in + ((size_t)b * 128 + t) * 512;
    #pragma unroll
    for (int k = 0; k < 4; ++k) {
        int d = threadIdx.x + 128 * k;
        ushort a, m, l;
        split3(ac[d] * src[d] + ac[512 + d], a, m, l);
        x0[(size_t)beta * 512 + d] = a;
        x1[(size_t)beta * 512 + d] = m;
        x2[(size_t)beta * 512 + d] = l;
    }
}

// ---------------- xg GEMM (3-split, 6 products): C[dir][m][n] fp32 ----------------
__global__ __launch_bounds__(256) void gemm6_k(const ushort* __restrict__ A0, const ushort* __restrict__ A1,
                                               const ushort* __restrict__ A2,
                                               const ushort* __restrict__ W0, const ushort* __restrict__ W1,
                                               const ushort* __restrict__ W2,
                                               float* __restrict__ C, int K) {
    const int dir = blockIdx.z;
    const ushort* Wp0 = W0 + (size_t)dir * 2048 * K;
    const ushort* Wp1 = W1 + (size_t)dir * 2048 * K;
    const ushort* Wp2 = W2 + (size_t)dir * 2048 * K;
    const int wave = threadIdx.x >> 6, lane = threadIdx.x & 63;
    const int l15 = lane & 15, kq = lane >> 4;
    const int m0 = blockIdx.y * 128 + (wave >> 1) * 64;
    const int n0 = blockIdx.x * 128 + (wave & 1) * 64;
    f32x4 acc[4][4];
    #pragma unroll
    for (int i = 0; i < 4; ++i)
        #pragma unroll
        for (int j = 0; j < 4; ++j) acc[i][j] = (f32x4){0.f, 0.f, 0.f, 0.f};
    for (int k0 = 0; k0 < K; k0 += 32) {
        bf16x8 a0[4], a1[4], a2[4], b0[4], b1[4], b2[4];
        #pragma unroll
        for (int i = 0; i < 4; ++i) {
            size_t o = (size_t)(m0 + i * 16 + l15) * K + k0 + kq * 8;
            a0[i] = *(const bf16x8*)(A0 + o);
            a1[i] = *(const bf16x8*)(A1 + o);
            a2[i] = *(const bf16x8*)(A2 + o);
        }
        #pragma unroll
        for (int j = 0; j < 4; ++j) {
            size_t o = (size_t)(n0 + j * 16 + l15) * K + k0 + kq * 8;
            b0[j] = *(const bf16x8*)(Wp0 + o);
            b1[j] = *(const bf16x8*)(Wp1 + o);
            b2[j] = *(const bf16x8*)(Wp2 + o);
        }
        #pragma unroll
        for (int i = 0; i < 4; ++i)
            #pragma unroll
            for (int j = 0; j < 4; ++j) {
                acc[i][j] = __builtin_amdgcn_mfma_f32_16x16x32_bf16(a2[i], b0[j], acc[i][j], 0, 0, 0);
                acc[i][j] = __builtin_amdgcn_mfma_f32_16x16x32_bf16(a1[i], b1[j], acc[i][j], 0, 0, 0);
                acc[i][j] = __builtin_amdgcn_mfma_f32_16x16x32_bf16(a0[i], b2[j], acc[i][j], 0, 0, 0);
                acc[i][j] = __builtin_amdgcn_mfma_f32_16x16x32_bf16(a1[i], b0[j], acc[i][j], 0, 0, 0);
                acc[i][j] = __builtin_amdgcn_mfma_f32_16x16x32_bf16(a0[i], b1[j], acc[i][j], 0, 0, 0);
                acc[i][j] = __builtin_amdgcn_mfma_f32_16x16x32_bf16(a0[i], b0[j], acc[i][j], 0, 0, 0);
            }
    }
    #pragma unroll
    for (int i = 0; i < 4; ++i)
        #pragma unroll
        for (int j = 0; j < 4; ++j)
            #pragma unroll
            for (int r = 0; r < 4; ++r)
                C[(size_t)dir * 8192 * 2048 + (size_t)(m0 + i * 16 + kq * 4 + r) * 2048 + n0 + j * 16 + l15]
                    = acc[i][j][r];
}

// ---------------- in-place row LayerNorm fp32, rows of 2048; grid (8192,2) ----------------
__global__ __launch_bounds__(256) void ln_rows32_k(float* __restrict__ X, const float* __restrict__ lng,
                                                   const float* __restrict__ lnb) {
    __shared__ float red[12];
    const int dir = blockIdx.y;
    float* row = X + ((size_t)dir * 8192 + blockIdx.x) * 2048;
    const float* g = lng + dir * 4608;
    const float* bb = lnb + dir * 4608;
    const int tid = threadIdx.x;
    float4 v0 = ((const float4*)row)[tid], v1 = ((const float4*)row)[tid + 256];
    float s1 = v0.x + v0.y + v0.z + v0.w + v1.x + v1.y + v1.z + v1.w;
    float s2 = v0.x * v0.x + v0.y * v0.y + v0.z * v0.z + v0.w * v0.w
             + v1.x * v1.x + v1.y * v1.y + v1.z * v1.z + v1.w * v1.w;
    blockReduceSum2(s1, s2, red);
    float m = s1 * (1.f / 2048.f);
    float rs = rsqrtf(s2 * (1.f / 2048.f) - m * m + LN_EPS);
    float4 g0 = ((const float4*)g)[tid],  g1 = ((const float4*)g)[tid + 256];
    float4 b0 = ((const float4*)bb)[tid], b1 = ((const float4*)bb)[tid + 256];
    float4 o0, o1;
    o0.x = (v0.x - m) * rs * g0.x + b0.x; o0.y = (v0.y - m) * rs * g0.y + b0.y;
    o0.z = (v0.z - m) * rs * g0.z + b0.z; o0.w = (v0.w - m) * rs * g0.w + b0.w;
    o1.x = (v1.x - m) * rs * g1.x + b1.x; o1.y = (v1.y - m) * rs * g1.y + b1.y;
    o1.z = (v1.z - m) * rs * g1.z + b1.z; o1.w = (v1.w - m) * rs * g1.w + b1.w;
    ((float4*)row)[tid] = o0;
    ((float4*)row)[tid + 256] = o1;
}

// ---------------- per-dir grid barrier (64 blocks each) ----------------
// Data published via sc1 write-through stores -> release is just vmcnt drain.
// INV=true only when the next phase reads cross-block data via NORMAL loads.
template <bool INV>
__device__ __forceinline__ void gbar4(unsigned int* flags, int dirB, unsigned e) {
    __builtin_amdgcn_s_waitcnt(0);
    __syncthreads();
    if (threadIdx.x == 0)
        st_flag(&flags[blockIdx.x * 16], e);
    if (threadIdx.x < 64) {
        while (ld_flag(&flags[(dirB * 64 + threadIdx.x) * 16]) < e)
            __builtin_amdgcn_s_sleep(2);
    }
    __syncthreads();
    if (INV)
        __builtin_amdgcn_fence(__ATOMIC_ACQUIRE, "agent");   // buffer_inv
}

// ---------------- LSTM scan, one layer, both dirs; 128x256 ----------------
// Phase A: block beta -> (dir=beta>>6) gate cols (beta&63)*32..+31, all 64 rows.
//   W_hh in REGISTERS (48 bf16x8/wave); h via normal cached loads (fresh after
//   the step-end inv); gates written via sc1. xg for phase B prefetched here.
// Phase B: block beta -> row (dir, b=beta&63); thread owns gate cols 2t,2t+1.
//   Gates read via sc1 u64 (no inv needed mid-step); h written via sc1.
__global__ __launch_bounds__(256, 1) void lstm_scan6_k(
    const float* __restrict__ xg,
    const ushort* __restrict__ w0, const ushort* __restrict__ w1, const ushort* __restrict__ w2,
    const float* __restrict__ lng, const float* __restrict__ lnb,
    ushort* __restrict__ hb0, ushort* __restrict__ hb1, ushort* __restrict__ hb2,
    float* __restrict__ graw,
    ushort* __restrict__ hs0, ushort* __restrict__ hs1, ushort* __restrict__ hs2,
    unsigned int* __restrict__ flags) {
    __shared__ float red[12];
    const int beta = blockIdx.x, tid = threadIdx.x;
    const int dirB = beta >> 6, bB = beta & 63;
    const int wave = tid >> 6, lane = tid & 63, l15 = lane & 15, kq = lane >> 4;
    const size_t hro = (size_t)(dirB * 64 + bB) * 512;
    // zero own h row via sc1 (published by first barrier)
    st_u32_c((unsigned*)(hb0 + hro) + tid, 0u);
    st_u32_c((unsigned*)(hb1 + hro) + tid, 0u);
    st_u32_c((unsigned*)(hb2 + hro) + tid, 0u);
    float c0 = 0.f, c1 = 0.f;
    const float* g_hh = lng + dirB * 4608 + 2048;
    const float* b_hh = lnb + dirB * 4608 + 2048;
    const float2 gcv = ((const float2*)(lng + dirB * 4608 + 4096))[tid];
    const float2 bcv = ((const float2*)(lnb + dirB * 4608 + 4096))[tid];
    // phase-A tile assignment: 4 waves cover 64 rows x 32 cols
    const int jj = wave >> 1, ip = wave & 1;
    const int nn = bB * 32 + jj * 16;
    const ushort* h0d = hb0 + (size_t)dirB * 64 * 512;
    const ushort* h1d = hb1 + (size_t)dirB * 64 * 512;
    const ushort* h2d = hb2 + (size_t)dirB * 64 * 512;
    float* gr = graw + dirB * 64 * 2048;
    // ---- preload W_hh fragments into registers: 16 k-tiles x 3 planes ----
    bf16x8 wr[16][3];
    {
        const ushort* w0d = w0 + (size_t)dirB * 2048 * 512;
        const ushort* w1d = w1 + (size_t)dirB * 2048 * 512;
        const ushort* w2d = w2 + (size_t)dirB * 2048 * 512;
        #pragma unroll
        for (int kt = 0; kt < 16; ++kt) {
            size_t wo = (size_t)(nn + l15) * 512 + kt * 32 + kq * 8;
            wr[kt][0] = *(const bf16x8*)(w0d + wo);
            wr[kt][1] = *(const bf16x8*)(w1d + wo);
            wr[kt][2] = *(const bf16x8*)(w2d + wo);
        }
    }
    unsigned int e = 0;
    gbar4<true>(flags, dirB, ++e);
    for (int s = 0; s < 128; ++s) {
        const int time = dirB ? (127 - s) : s;
        // prefetch xg for this step's phase B (independent of barrier data)
        const float2* xr = (const float2*)(xg + ((size_t)dirB * 8192 + (size_t)time * 64 + bB) * 2048);
        float2 xv[4];
        #pragma unroll
        for (int j = 0; j < 4; ++j) xv[j] = xr[tid + 256 * j];
        // -------- phase A: 6-product MFMA, W in regs, h cached (post-inv) --------
        {
            f32x4 acc[2];
            acc[0] = (f32x4){0.f, 0.f, 0.f, 0.f};
            acc[1] = (f32x4){0.f, 0.f, 0.f, 0.f};
            #pragma unroll
            for (int kt = 0; kt < 16; ++kt) {
                #pragma unroll
                for (int ii = 0; ii < 2; ++ii) {
                    size_t ho = (size_t)(ip * 32 + ii * 16 + l15) * 512 + kt * 32 + kq * 8;
                    bf16x8 a0 = *(const bf16x8*)(h0d + ho);
                    bf16x8 a1 = *(const bf16x8*)(h1d + ho);
                    bf16x8 a2 = *(const bf16x8*)(h2d + ho);
                    acc[ii] = __builtin_amdgcn_mfma_f32_16x16x32_bf16(a2, wr[kt][0], acc[ii], 0, 0, 0);
                    acc[ii] = __builtin_amdgcn_mfma_f32_16x16x32_bf16(a1, wr[kt][1], acc[ii], 0, 0, 0);
                    acc[ii] = __builtin_amdgcn_mfma_f32_16x16x32_bf16(a0, wr[kt][2], acc[ii], 0, 0, 0);
                    acc[ii] = __builtin_amdgcn_mfma_f32_16x16x32_bf16(a1, wr[kt][0], acc[ii], 0, 0, 0);
                    acc[ii] = __builtin_amdgcn_mfma_f32_16x16x32_bf16(a0, wr[kt][1], acc[ii], 0, 0, 0);
                    acc[ii] = __builtin_amdgcn_mfma_f32_16x16x32_bf16(a0, wr[kt][0], acc[ii], 0, 0, 0);
                }
            }
            #pragma unroll
            for (int ii = 0; ii < 2; ++ii)
                #pragma unroll
                for (int r = 0; r < 4; ++r)
                    st_f32_c(&gr[(ip * 32 + ii * 16 + kq * 4 + r) * 2048 + nn + l15], acc[ii][r]);
        }
        gbar4<false>(flags, dirB, ++e);   // gates read via sc1 below: no inv
        // -------- phase B: own row; thread owns gate cols 2t, 2t+1 --------
        {
            const float* grow = gr + bB * 2048;
            const int base = 2 * tid;
            float v[8];
            #pragma unroll
            for (int j = 0; j < 4; ++j) {
                union { unsigned long long q; float f[2]; } c;
                c.q = ld_u64_c(&grow[j * 512 + base]);
                v[2 * j] = c.f[0]; v[2 * j + 1] = c.f[1];
            }
            float s1 = 0.f, s2 = 0.f;
            #pragma unroll
            for (int k = 0; k < 8; ++k) { s1 += v[k]; s2 += v[k] * v[k]; }
            blockReduceSum2(s1, s2, red);
            float mu = s1 * (1.f / 2048.f);
            float rs = rsqrtf(s2 * (1.f / 2048.f) - mu * mu + LN_EPS);
            float nv[8];
            #pragma unroll
            for (int j = 0; j < 4; ++j) {
                float2 gh = ((const float2*)g_hh)[tid + 256 * j];
                float2 bh = ((const float2*)b_hh)[tid + 256 * j];
                nv[2 * j]     = xv[j].x + (v[2 * j]     - mu) * rs * gh.x + bh.x;
                nv[2 * j + 1] = xv[j].y + (v[2 * j + 1] - mu) * rs * gh.y + bh.y;
            }
            float si0 = 1.f / (1.f + expf(-nv[0])), si1 = 1.f / (1.f + expf(-nv[1]));
            float sf0 = 1.f / (1.f + expf(-nv[2])), sf1 = 1.f / (1.f + expf(-nv[3]));
            c0 = sf0 * c0 + si0 * tanhf(nv[4]);
            c1 = sf1 * c1 + si1 * tanhf(nv[5]);
            float t1 = c0 + c1, t2 = c0 * c0 + c1 * c1;
            blockReduceSum2(t1, t2, red);
            float mc = t1 * (1.f / 512.f);
            float rc = rsqrtf(t2 * (1.f / 512.f) - mc * mc + LN_EPS);
            float so0 = 1.f / (1.f + expf(-nv[6])), so1 = 1.f / (1.f + expf(-nv[7]));
            float h0v = so0 * tanhf((c0 - mc) * rc * gcv.x + bcv.x);
            float h1v = so1 * tanhf((c1 - mc) * rc * gcv.y + bcv.y);
            ushort a0, m0, l0, a1, m1, l1;
            split3(h0v, a0, m0, l0);
            split3(h1v, a1, m1, l1);
            unsigned p0 = (unsigned)a0 | ((unsigned)a1 << 16);
            unsigned p1 = (unsigned)m0 | ((unsigned)m1 << 16);
            unsigned p2 = (unsigned)l0 | ((unsigned)l1 << 16);
            st_u32_c((unsigned*)(hb0 + hro) + tid, p0);
            st_u32_c((unsigned*)(hb1 + hro) + tid, p1);
            st_u32_c((unsigned*)(hb2 + hro) + tid, p2);
            size_t oro = ((size_t)time * 64 + bB) * 1024 + dirB * 512;
            ((unsigned*)(hs0 + oro))[tid] = p0;    // hs read after kernel only
            ((unsigned*)(hs1 + oro))[tid] = p1;
            ((unsigned*)(hs2 + oro))[tid] = p2;
        }
        gbar4<true>(flags, dirB, ++e);    // phase A reads h via cached loads: inv
    }
}

// ---------------- BatchNorm 2 (reads 3-split hs) ----------------
__global__ __launch_bounds__(256) void bn2_stats3_k(const ushort* __restrict__ h0, const ushort* __restrict__ h1,
                                                    const ushort* __restrict__ h2, float* __restrict__ st) {
    int t = blockIdx.x, tid = threadIdx.x;
    float s1[4] = {0, 0, 0, 0}, s2[4] = {0, 0, 0, 0};
    size_t base = (size_t)t * 64 * 1024;
    for (int b = 0; b < 64; ++b) {
        #pragma unroll
        for (int k = 0; k < 4; ++k) {
            size_t o = base + b * 1024 + tid + 256 * k;
            float x = bf2f(h0[o]) + bf2f(h1[o]) + bf2f(h2[o]);
            s1[k] += x; s2[k] += x * x;
        }
    }
    #pragma unroll
    for (int k = 0; k < 4; ++k) {
        atomicAdd(&st[tid + 256 * k], s1[k]);
        atomicAdd(&st[1024 + tid + 256 * k], s2[k]);
    }
}

__global__ void bn2_final_k(const float* __restrict__ st, const float* __restrict__ g,
                            const float* __restrict__ bb, float* __restrict__ ac) {
    #pragma unroll
    for (int k = 0; k < 4; ++k) {
        int h = threadIdx.x + 256 * k;
        float m = st[h] * (1.f / 8192.f);
        float v = st[1024 + h] * (1.f / 8192.f) - m * m;
        float a = g[h] * rsqrtf(v + LN_EPS);
        ac[h] = a; ac[1024 + h] = bb[h] - m * a;
    }
}

__global__ __launch_bounds__(256) void bn2_apply3_k(const ushort* __restrict__ h0, const ushort* __restrict__ h1,
                                                    const ushort* __restrict__ h2, const float* __restrict__ ac,
                                                    float* __restrict__ y) {
    int beta = blockIdx.x;        // b*128+t
    int b = beta >> 7, t = beta & 127;
    size_t so = ((size_t)t * 64 + b) * 1024;
    float* dst = y + (size_t)beta * 1024;
    #pragma unroll
    for (int k = 0; k < 4; ++k) {
        int h = threadIdx.x + 256 * k;
        float x = bf2f(h0[so + h]) + bf2f(h1[so + h]) + bf2f(h2[so + h]);
        dst[h] = ac[h] * x + ac[1024 + h];
    }
}

// ---------------- attention (fp32) ----------------
__global__ __launch_bounds__(64) void att_scores_k(const float* __restrict__ y, const float* __restrict__ wo,
                                                   const float* __restrict__ bo, const float* __restrict__ uo,
                                                   float* __restrict__ sc) {
    int row = blockIdx.x;     // b*128+t
    int a = threadIdx.x;
    const float* yr = y + (size_t)row * 1024;
    float acc = bo[a];
    for (int h = 0; h < 1024; h += 4) {
        float4 yv = *(const float4*)(yr + h);
        acc += yv.x * wo[(h + 0) * 64 + a];
        acc += yv.y * wo[(h + 1) * 64 + a];
        acc += yv.z * wo[(h + 2) * 64 + a];
        acc += yv.w * wo[(h + 3) * 64 + a];
    }
    float p = tanhf(acc) * uo[a];
    #pragma unroll
    for (int off = 32; off > 0; off >>= 1) p += __shfl_down(p, off, 64);
    if (a == 0) sc[row] = p;
}

__global__ __launch_bounds__(128) void att_softmax_k(const float* __restrict__ sc, float* __restrict__ al) {
    __shared__ float red[8];
    int b = blockIdx.x, t = threadIdx.x;
    int lane = t & 63, w = t >> 6;
    float v = sc[b * 128 + t];
    float m = v;
    #pragma unroll
    for (int off = 32; off > 0; off >>= 1) m = fmaxf(m, __shfl_down(m, off, 64));
    if (lane == 0) red[w] = m;
    __syncthreads();
    m = fmaxf(red[0], red[1]);
    float e = expf(v - m);
    float sum = e;
    #pragma unroll
    for (int off = 32; off > 0; off >>= 1) sum += __shfl_down(sum, off, 64);
    if (lane == 0) red[2 + w] = sum;
    __syncthreads();
    sum = red[2] + red[3];
    al[b * 128 + t] = e / sum;
}

__global__ __launch_bounds__(256) void att_pool_k(const float* __restrict__ y, const float* __restrict__ al,
                                                  float* __restrict__ pooled) {
    int b = blockIdx.x, tid = threadIdx.x;
    float acc[4] = {0, 0, 0, 0};
    const float* yb = y + (size_t)b * 128 * 1024;
    for (int t = 0; t < 128; ++t) {
        float a = al[b * 128 + t];
        #pragma unroll
        for (int k = 0; k < 4; ++k) acc[k] += a * yb[t * 1024 + tid + 256 * k];
    }
    #pragma unroll
    for (int k = 0; k < 4; ++k) pooled[b * 1024 + tid + 256 * k] = acc[k];
}

__global__ __launch_bounds__(256) void out_gemv_k(const float* __restrict__ pooled, const float* __restrict__ W,
                                                  float* __restrict__ out) {
    int b = blockIdx.x, tid = threadIdx.x;
    const float* pb = pooled + b * 1024;
    #pragma unroll
    for (int rep = 0; rep < 2; ++rep) {
        int c = tid + rep * 256;
        if (c < 501) {
            float acc = W[(size_t)1024 * 501 + c];   // bias row (emb padded with 1)
            for (int h = 0; h < 1024; ++h) acc += pb[h] * W[(size_t)h * 501 + c];
            out[b * 501 + c] = acc;
        }
    }
}

extern "C" void kernel_launch(void* const* d_in, const int* in_sizes, int n_in,
                              void* d_out, int out_size, void* d_ws, size_t ws_size,
                              hipStream_t stream) {
    (void)in_sizes; (void)n_in; (void)out_size; (void)ws_size;
    const float* in_x  = (const float*)d_in[0];
    const float* bn1g  = (const float*)d_in[1];
    const float* bn1b  = (const float*)d_in[2];
    const float* bn2g  = (const float*)d_in[3];
    const float* bn2b  = (const float*)d_in[4];
    const float* w_ih0 = (const float*)d_in[5];
    const float* w_hh0 = (const float*)d_in[6];
    const float* lng0  = (const float*)d_in[7];
    const float* lnb0  = (const float*)d_in[8];
    const float* w_ih1 = (const float*)d_in[9];
    const float* w_hh1 = (const float*)d_in[10];
    const float* lng1  = (const float*)d_in[11];
    const float* lnb1  = (const float*)d_in[12];
    const float* w_om  = (const float*)d_in[13];
    const float* b_om  = (const float*)d_in[14];
    const float* u_om  = (const float*)d_in[15];
    const float* Wf    = (const float*)d_in[16];
    float* out = (float*)d_out;

    // ---- workspace: ~238 MiB of the 256 MiB budget ----
    char* ws = (char*)d_ws;
    size_t off = 0;
    auto alloc = [&](size_t bytes) { size_t o = off; off += (bytes + 255) & ~(size_t)255; return o; };
    float*  xg     = (float*)(ws + alloc(2ull * 8192 * 2048 * 4));    // 134.2 MB; ybuf aliases later
    ushort* hs0_0  = (ushort*)(ws + alloc(8192ull * 1024 * 2));       // hs0 3-split, 50.3 MB
    ushort* hs0_1  = (ushort*)(ws + alloc(8192ull * 1024 * 2));
    ushort* hs0_2  = (ushort*)(ws + alloc(8192ull * 1024 * 2));
    char*   hs1reg = ws + alloc(3ull * 8192 * 1024 * 2);              // hs1 region, 50.3 MB (aliased below)
    ushort* WH1_0  = (ushort*)(ws + alloc(2ull * 2048 * 512 * 2));    // W_hh1 3-split (live during scan L1)
    ushort* WH1_1  = (ushort*)(ws + alloc(2ull * 2048 * 512 * 2));
    ushort* WH1_2  = (ushort*)(ws + alloc(2ull * 2048 * 512 * 2));
    float*  graw   = (float*)(ws + alloc(2ull * 64 * 2048 * 4));      // 1 MB
    ushort* hb0    = (ushort*)(ws + alloc(2ull * 64 * 512 * 2));
    ushort* hb1    = (ushort*)(ws + alloc(2ull * 64 * 512 * 2));
    ushort* hb2    = (ushort*)(ws + alloc(2ull * 64 * 512 * 2));
    float*  st1    = (float*)(ws + alloc(1024 * 4));
    float*  ac1    = (float*)(ws + alloc(1024 * 4));
    float*  st2    = (float*)(ws + alloc(2048 * 4));
    float*  ac2    = (float*)(ws + alloc(2048 * 4));
    float*  sc     = (float*)(ws + alloc(8192 * 4));
    float*  al     = (float*)(ws + alloc(8192 * 4));
    float*  pooled = (float*)(ws + alloc(64ull * 1024 * 4));
    unsigned int* bar0 = (unsigned int*)(ws + alloc(128 * 16 * 4));   // flags, 64B stride
    unsigned int* bar1 = (unsigned int*)(ws + alloc(128 * 16 * 4));
    // hs1 region sub-aliases (all dead before scan L1 writes hs1):
    ushort* hs1_0 = (ushort*)hs1reg;
    ushort* hs1_1 = (ushort*)(hs1reg + 16777216);
    ushort* hs1_2 = (ushort*)(hs1reg + 33554432);
    ushort* xn0   = (ushort*)(hs1reg + 0);           // xn: bn1 -> gemm L0
    ushort* xn1   = (ushort*)(hs1reg + 8388608);
    ushort* xn2   = (ushort*)(hs1reg + 16777216);
    ushort* WI0_0 = (ushort*)(hs1reg + 25165824);    // W_ih0: conv -> gemm L0
    ushort* WI0_1 = (ushort*)(hs1reg + 29360128);
    ushort* WI0_2 = (ushort*)(hs1reg + 33554432);
    ushort* WH0_0 = (ushort*)(hs1reg + 37748736);    // W_hh0: conv -> scan L0
    ushort* WH0_1 = (ushort*)(hs1reg + 41943040);
    ushort* WH0_2 = (ushort*)(hs1reg + 46137344);    // ends at 50331648 = region end
    ushort* WI1_0 = (ushort*)(hs1reg + 0);           // W_ih1: after xn dead -> gemm L1
    ushort* WI1_1 = (ushort*)(hs1reg + 8388608);
    ushort* WI1_2 = (ushort*)(hs1reg + 16777216);
    float*  ybuf  = (float*)xg;                      // 33.6 MB fp32, xg dead after scan L1

    hipMemsetAsync(st1, 0, 1024 * 4, stream);
    hipMemsetAsync(st2, 0, 2048 * 4, stream);
    hipMemsetAsync(bar0, 0, 128 * 16 * 4, stream);
    hipMemsetAsync(bar1, 0, 128 * 16 * 4, stream);

    // stage layer-0 weights (3-split)
    conv_split3_k<<<2048, 256, 0, stream>>>(w_ih0, WI0_0, WI0_1, WI0_2, 2097152 / 4);
    conv_split3_k<<<2048, 256, 0, stream>>>(w_hh0, WH0_0, WH0_1, WH0_2, 2097152 / 4);

    // BN1 + transpose to (T,B,V), 3-split
    bn1_stats_k<<<64, 256, 0, stream>>>(in_x, st1);
    bn1_final_k<<<2, 256, 0, stream>>>(st1, bn1g, bn1b, ac1);
    bn1_apply3_k<<<8192, 128, 0, stream>>>(in_x, ac1, xn0, xn1, xn2);

    // ---- layer 0 ----
    gemm6_k<<<dim3(16, 64, 2), 256, 0, stream>>>(xn0, xn1, xn2, WI0_0, WI0_1, WI0_2, xg, 512);
    ln_rows32_k<<<dim3(8192, 2), 256, 0, stream>>>(xg, lng0, lnb0);
    lstm_scan6_k<<<128, 256, 0, stream>>>(xg, WH0_0, WH0_1, WH0_2, lng0, lnb0,
                                          hb0, hb1, hb2, graw, hs0_0, hs0_1, hs0_2, bar0);

    // stage layer-1 weights (xn / WI0 regions now dead)
    conv_split3_k<<<4096, 256, 0, stream>>>(w_ih1, WI1_0, WI1_1, WI1_2, 4194304 / 4);
    conv_split3_k<<<2048, 256, 0, stream>>>(w_hh1, WH1_0, WH1_1, WH1_2, 2097152 / 4);

    // ---- layer 1 ----
    gemm6_k<<<dim3(16, 64, 2), 256, 0, stream>>>(hs0_0, hs0_1, hs0_2, WI1_0, WI1_1, WI1_2, xg, 1024);
    ln_rows32_k<<<dim3(8192, 2), 256, 0, stream>>>(xg, lng1, lnb1);
    lstm_scan6_k<<<128, 256, 0, stream>>>(xg, WH1_0, WH1_1, WH1_2, lng1, lnb1,
                                          hb0, hb1, hb2, graw, hs1_0, hs1_1, hs1_2, bar1);

    // BN2 -> y fp32 (B,T,2H); ybuf aliases dead xg
    bn2_stats3_k<<<128, 256, 0, stream>>>(hs1_0, hs1_1, hs1_2, st2);
    bn2_final_k<<<1, 256, 0, stream>>>(st2, bn2g, bn2b, ac2);
    bn2_apply3_k<<<8192, 256, 0, stream>>>(hs1_0, hs1_1, hs1_2, ac2, ybuf);

    // attention + output
    att_scores_k<<<8192, 64, 0, stream>>>(ybuf, w_om, b_om, u_om, sc);
    att_softmax_k<<<64, 128, 0, stream>>>(sc, al);
    att_pool_k<<<64, 256, 0, stream>>>(ybuf, al, pooled);
    out_gemv_k<<<64, 256, 0, stream>>>(pooled, Wf, out);
}